// Round 9
// baseline (676.919 us; speedup 1.0000x reference)
//
#include <hip/hip_runtime.h>
#include <hip/hip_bf16.h>

typedef __attribute__((ext_vector_type(8))) short short8;
typedef __attribute__((ext_vector_type(4))) short s16x4;
typedef __attribute__((ext_vector_type(4))) float f32x4;

#define D_H   224
#define D_W   224
#define D_HW  50176
#define SCALE 0.17677669529663687f  // 32^-0.5

// weight sub-offsets (shorts, relative to weight base)
#define WO_QKVW  0        // 27648
#define WO_PROJW 27648    // 9216
#define WO_W1    36864    // 36864
#define WO_W2    73728    // 36864
#define WO_TOT   110592

// big-workspace layout (shorts)
#define XT_SH 0                       // 8*224*224*96 = 38535168 bf16
#define YT_SH 38535168                // same size
#define W_SH  77070336                // weights
#define TAB_SH (W_SH + WO_TOT)        // bias table: 64*64*4 f32 = 65536 B
#define WS_NEED ((size_t)(77070336 + 110592) * 2 + 65536)

static __device__ __forceinline__ short f2s(float v) {
    union { __hip_bfloat16 b; short s; } u; u.b = __float2bfloat16(v); return u.s;
}
static __device__ __forceinline__ float s2f(short s) {
    union { short s; __hip_bfloat16 b; } u; u.s = s; return __bfloat162float(u.b);
}

#define MFMA(a, b, c) __builtin_amdgcn_mfma_f32_16x16x32_bf16((a), (b), (c), 0, 0, 0)

static __device__ __forceinline__ short8 normfrag(const short* p, const float* g,
                                                  const float* b, int c0, float m, float rs) {
    short8 r = *(const short8*)p;
    short8 o;
#pragma unroll
    for (int j = 0; j < 8; j++) o[j] = f2s((s2f(r[j]) - m) * rs * g[c0 + j] + b[c0 + j]);
    return o;
}

// A&S 7.1.26 erf approximation: max abs err ~1.5e-7 (result stored to bf16 anyway)
static __device__ __forceinline__ float erf_fast(float x) {
    float a = fabsf(x);
    float t = __builtin_amdgcn_rcpf(1.f + 0.3275911f * a);
    float p = t * (0.254829592f + t * (-0.284496736f + t * (1.421413741f +
              t * (-1.453152027f + t * 1.061405429f))));
    float y = 1.f - p * __expf(-a * a);
    return copysignf(y, x);
}

// ---------------------------------------------------------------------------
// K0 (v2): blocks 0..107: f32 -> bf16 weight conversion.
//          blocks 108..123: rel-pos bias table tabf[n*64+m][0..2] = relt rows
//          (clamped-token indexing folded in; kills /7 math in k_attn).
// ---------------------------------------------------------------------------
__global__ __launch_bounds__(256) void k_prep(
    const float* __restrict__ qkvw, const float* __restrict__ projw,
    const float* __restrict__ w1, const float* __restrict__ w2,
    const float* __restrict__ relt, short* __restrict__ ws, float* __restrict__ tabf)
{
    const int bid = blockIdx.x;
    if (bid < 108) {
        int i4 = bid * 256 + threadIdx.x;            // 27648 f32x4 groups total
        const float* src; int off;
        if (i4 < 6912)        { src = qkvw;  off = 0; }
        else if (i4 < 9216)   { src = projw; off = 6912; }
        else if (i4 < 18432)  { src = w1;    off = 9216; }
        else                  { src = w2;    off = 18432; }
        f32x4 v = *(const f32x4*)&src[(i4 - off) * 4];
        s16x4 s;
#pragma unroll
        for (int j = 0; j < 4; j++) s[j] = f2s(v[j]);
        *(s16x4*)&ws[i4 * 4] = s;
    } else {
        int i = (bid - 108) * 256 + threadIdx.x;     // 0..4095 = (n,m)
        int n = i >> 6, m = i & 63;
        int nn = (n < 49) ? n : 48;
        int mm = (m < 49) ? m : 48;
        int r1 = nn / 7, c1 = nn - r1 * 7;
        int r2 = mm / 7, c2 = mm - r2 * 7;
        int ri = ((r1 - r2 + 6) * 13 + (c1 - c2 + 6)) * 3;
        f32x4 o = { relt[ri + 0], relt[ri + 1], relt[ri + 2], 0.f };
        *(f32x4*)&tabf[i * 4] = o;
    }
}

// ---------------------------------------------------------------------------
// KT (v3): x (B,C,H,W) f32 -> xt (B,H,W,C) bf16.
//   In-register 4x4 micro-transpose: 4x f32x4 coalesced loads (4 planes x 4 w)
//   -> 4x s16x4 LDS writes into XOR-swizzled [224][128] tile (slot=c4^(w&31)).
//   Load instrs 84 -> 24 per thread, all 16B. Readout = v1 (vector s16x4).
// ---------------------------------------------------------------------------
__global__ __launch_bounds__(256) void k_t(const float* __restrict__ x, short* __restrict__ xt)
{
    __shared__ short tile[224][128];     // 57344 B; 32 slots x 4 shorts per row
    const int tid = threadIdx.x;
    const int bh = blockIdx.x;
    const int b = bh / 224, h = bh - b * 224;
    const int pbase = (b * 96) * D_HW + h * 224;

#pragma unroll
    for (int k = 0; k < 6; k++) {
        int idx = tid + k * 256;         // valid < 1344 = 24 c-quads * 56 w-quads
        if (idx < 1344) {
            int c4 = idx / 56, w4 = idx - c4 * 56;
            float vv[4][4];
#pragma unroll
            for (int j = 0; j < 4; j++) {
                f32x4 v = *(const f32x4*)&x[pbase + (c4 * 4 + j) * D_HW + w4 * 4];
#pragma unroll
                for (int i = 0; i < 4; i++) vv[j][i] = v[i];
            }
#pragma unroll
            for (int i = 0; i < 4; i++) {
                int w = w4 * 4 + i;
                s16x4 o;
#pragma unroll
                for (int j = 0; j < 4; j++) o[j] = f2s(vv[j][i]);
                *(s16x4*)&tile[w][(c4 ^ (w & 31)) * 4] = o;
            }
        }
    }
    __syncthreads();
    const int obase = ((b * 224 + h) * 224) * 96;
#pragma unroll
    for (int k = 0; k < 11; k++) {
        int idx = tid + k * 256;         // valid < 2688 = 224*12
        if (idx < 2688) {
            int w = idx / 12, s = idx - w * 12;
            int kk = w & 31;
            s16x4 a = *(const s16x4*)&tile[w][((2 * s) ^ kk) * 4];
            s16x4 c = *(const s16x4*)&tile[w][((2 * s + 1) ^ kk) * 4];
            short8 o;
            o[0] = a[0]; o[1] = a[1]; o[2] = a[2]; o[3] = a[3];
            o[4] = c[0]; o[5] = c[1]; o[6] = c[2]; o[7] = c[3];
            *(short8*)&xt[obase + w * 96 + s * 8] = o;
        }
    }
}

// ---------------------------------------------------------------------------
// K1 (v7): one block per window, token-major bf16 in/out.
//   4 barriers; 2-deep register prefetch of direct-global W frags;
//   rel-pos bias via precomputed f32x4 table (no /7 math, 16 vector loads).
// ---------------------------------------------------------------------------
__global__ __launch_bounds__(256, 3) void k_attn_t(
    const short* __restrict__ xt, const float* __restrict__ n1g, const float* __restrict__ n1b,
    const float* __restrict__ qkvb, const float* __restrict__ tabf,
    const float* __restrict__ projb, const short* __restrict__ wsw, short* __restrict__ yt)
{
    __shared__ short qk[64][200];                    // Q(0..95 pre-scaled) K(96..191); PV/proj out
    __shared__ __align__(16) short region[11520];    // [ps 4608][vt 6912] shorts
    short (*xs)[104] = (short(*)[104])region;        // raw tokens, pre-QKV only
    short (*ps)[72]  = (short(*)[72])region;         // P matrix (heads phase)
    short (*vt)[72]  = (short(*)[72])(region + 4608);// V d-major (96 rows x 72)
    __shared__ int   cnt_s[64];
    __shared__ float mean_s[64], rstd_s[64];

    const int tid  = threadIdx.x;
    const int wave = tid >> 6, lane = tid & 63;
    const int l16  = lane & 15, q8 = (lane >> 4) * 8, q4 = (lane >> 4) * 4;
    const int t0   = wave * 16;

    const short* qkvw_bf  = wsw + WO_QKVW;
    const short* projw_bf = wsw + WO_PROJW;

    const int wi = blockIdx.x;
    const int b  = wi >> 10, nw = wi & 1023;
    const int wh = nw >> 5, ww = nw & 31;
    const bool edge = (wh == 31) || (ww == 31);

    if (tid < 64) {
        int t = (tid < 49) ? tid : 48;
        int r = t / 7, c = t - r * 7;
        int sh = wh * 7 + r, sw = ww * 7 + c;
        int rh = (sh < 217) ? 0 : ((sh < 221) ? 1 : 2);
        int rw = (sw < 217) ? 0 : ((sw < 221) ? 1 : 2);
        cnt_s[tid] = rh * 3 + rw;
    }
    // ---- gather: 64 tokens x 12 16B-segments from xt ----
#pragma unroll
    for (int k = 0; k < 3; k++) {
        int idx = tid + k * 256;                     // < 768 = 64*12
        int t = idx / 12, s = idx - t * 12;
        short8 v = {0, 0, 0, 0, 0, 0, 0, 0};
        if (t < 49) {
            int r = t / 7, cc = t - r * 7;
            int hh = wh * 7 + r + 3;  if (hh >= D_H) hh -= D_H;
            int w2 = ww * 7 + cc + 3; if (w2 >= D_W) w2 -= D_W;
            v = *(const short8*)&xt[((b * 224 + hh) * 224 + w2) * 96 + s * 8];
        }
        *(short8*)&xs[t][s * 8] = v;
    }
    __syncthreads();                                 // [bar 1] xs + cnt_s visible

    // ---- LN1 stats: 4 lanes/token, own-wave rows ----
    {
        int t = tid >> 2, p = tid & 3;
        float s = 0.f, s2 = 0.f;
#pragma unroll
        for (int i = 0; i < 6; i++) {
            s16x4 v4 = *(const s16x4*)&xs[t][p * 24 + i * 4];
#pragma unroll
            for (int j = 0; j < 4; j++) { float v = s2f(v4[j]); s += v; s2 += v * v; }
        }
        s += __shfl_xor(s, 1); s2 += __shfl_xor(s2, 1);
        s += __shfl_xor(s, 2); s2 += __shfl_xor(s2, 2);
        if (p == 0) {
            float m = s * (1.f / 96.f);
            float var = s2 * (1.f / 96.f) - m * m;
            mean_s[t] = m; rstd_s[t] = rsqrtf(var + 1e-5f);
        }
    }
    // mean/rstd same-wave -> no barrier

    // ---- A-frags with fused normalize (own rows; xs dead after this) ----
    const float m0 = mean_s[t0 + l16], rs0 = rstd_s[t0 + l16];
    short8 a0 = normfrag(&xs[t0 + l16][q8],      n1g, n1b, q8,      m0, rs0);
    short8 a1 = normfrag(&xs[t0 + l16][32 + q8], n1g, n1b, 32 + q8, m0, rs0);
    short8 a2 = normfrag(&xs[t0 + l16][64 + q8], n1g, n1b, 64 + q8, m0, rs0);

    // issue first QKV W-group loads early (hide under barrier drain)
    short8 wA0, wA1, wA2, wB0, wB1, wB2;
    {
        const short* w = qkvw_bf + l16 * 96;         // g=0: jc=0, nt=0
        wA0 = *(const short8*)&w[q8];
        wA1 = *(const short8*)&w[32 + q8];
        wA2 = *(const short8*)&w[64 + q8];
    }
    __syncthreads();                                 // [bar 2] all xs reads done (vt overwrites)

    // ---- QKV: 18 groups, 2-deep register-pipelined W loads ----
#pragma unroll
    for (int g = 0; g < 18; g++) {
        const int jc = g / 6, nt = g - jc * 6;
        const int jj = nt * 16 + l16;
        if (g < 17) {
            int g2 = g + 1, jc2 = g2 / 6, nt2 = g2 - jc2 * 6;
            const short* w = qkvw_bf + (jc2 * 96 + nt2 * 16 + l16) * 96;
            wB0 = *(const short8*)&w[q8];
            wB1 = *(const short8*)&w[32 + q8];
            wB2 = *(const short8*)&w[64 + q8];
        }
        f32x4 acc = {0.f, 0.f, 0.f, 0.f};
        acc = MFMA(a0, wA0, acc);
        acc = MFMA(a1, wA1, acc);
        acc = MFMA(a2, wA2, acc);
        float bias = qkvb[jc * 96 + jj];
        if (jc == 0) {
#pragma unroll
            for (int r = 0; r < 4; r++) qk[t0 + q4 + r][jj] = f2s((acc[r] + bias) * SCALE);
        } else if (jc == 1) {
#pragma unroll
            for (int r = 0; r < 4; r++) qk[t0 + q4 + r][96 + jj] = f2s(acc[r] + bias);
        } else {
            s16x4 v4;
#pragma unroll
            for (int r = 0; r < 4; r++) v4[r] = f2s(acc[r] + bias);
            *(s16x4*)&vt[jj][t0 + q4] = v4;
        }
        wA0 = wB0; wA1 = wB1; wA2 = wB2;
    }

    // ---- per-lane rel-pos bias + mask: table lookups (f32x4), no index math ----
    float biasv[4][4][3];
#pragma unroll
    for (int nt = 0; nt < 4; nt++) {
        int m  = nt * 16 + l16;
        int cm = cnt_s[m];
#pragma unroll
        for (int r = 0; r < 4; r++) {
            int n = t0 + q4 + r;
            f32x4 t4 = *(const f32x4*)&tabf[(n * 64 + m) * 4];
            float mk = (edge && (cnt_s[n] != cm)) ? -100.f : 0.f;
            biasv[nt][r][0] = t4[0] + mk;
            biasv[nt][r][1] = t4[1] + mk;
            biasv[nt][r][2] = t4[2] + mk;
        }
    }
    const bool inval3 = (l16 != 0);

    __syncthreads();                                 // [bar 3] K + V visible to all waves

    // ---- attention heads: zero internal barriers ----
#pragma unroll
    for (int h = 0; h < 3; h++) {
        short8 aq = *(const short8*)&qk[t0 + l16][h * 32 + q8];  // own rows
        f32x4 sv[4];
#pragma unroll
        for (int nt = 0; nt < 4; nt++) {
            f32x4 z = {0.f, 0.f, 0.f, 0.f};
            sv[nt] = MFMA(aq, *(const short8*)&qk[nt * 16 + l16][96 + h * 32 + q8], z);
        }
        float mx[4] = {-1e30f, -1e30f, -1e30f, -1e30f};
#pragma unroll
        for (int nt = 0; nt < 4; nt++) {
#pragma unroll
            for (int r = 0; r < 4; r++) {
                float v = sv[nt][r] + biasv[nt][r][h];
                if (nt == 3 && inval3) v = -1e30f;
                sv[nt][r] = v;
                mx[r] = fmaxf(mx[r], v);
            }
        }
#pragma unroll
        for (int d = 1; d < 16; d <<= 1) {
#pragma unroll
            for (int r = 0; r < 4; r++) mx[r] = fmaxf(mx[r], __shfl_xor(mx[r], d));
        }
        float sm[4] = {0.f, 0.f, 0.f, 0.f};
#pragma unroll
        for (int nt = 0; nt < 4; nt++) {
#pragma unroll
            for (int r = 0; r < 4; r++) {
                float e = (nt == 3 && inval3) ? 0.f : __expf(sv[nt][r] - mx[r]);
                sv[nt][r] = e;
                sm[r] += e;
            }
        }
#pragma unroll
        for (int d = 1; d < 16; d <<= 1) {
#pragma unroll
            for (int r = 0; r < 4; r++) sm[r] += __shfl_xor(sm[r], d);
        }
        float inv[4];
#pragma unroll
        for (int r = 0; r < 4; r++) inv[r] = __builtin_amdgcn_rcpf(sm[r]);
#pragma unroll
        for (int nt = 0; nt < 4; nt++) {
#pragma unroll
            for (int r = 0; r < 4; r++)
                ps[t0 + q4 + r][nt * 16 + l16] = f2s(sv[nt][r] * inv[r]);   // own rows
        }
        short8 p0 = *(const short8*)&ps[t0 + l16][q8];
        short8 p1 = *(const short8*)&ps[t0 + l16][32 + q8];
#pragma unroll
        for (int nt = 0; nt < 2; nt++) {
            f32x4 acc = {0.f, 0.f, 0.f, 0.f};
            acc = MFMA(p0, *(const short8*)&vt[h * 32 + nt * 16 + l16][q8],      acc);
            acc = MFMA(p1, *(const short8*)&vt[h * 32 + nt * 16 + l16][32 + q8], acc);
            int d = nt * 16 + l16;
#pragma unroll
            for (int r = 0; r < 4; r++) {
                int t = t0 + q4 + r;
                if (t < 49) qk[t][h * 32 + d] = f2s(acc[r]);                // own rows
            }
        }
    }

    // ---- proj: 6 groups, 2-deep register-pipelined W loads ----
    {
        const short* w = projw_bf + l16 * 96;        // g=0
        wA0 = *(const short8*)&w[q8];
        wA1 = *(const short8*)&w[32 + q8];
        wA2 = *(const short8*)&w[64 + q8];
    }
    short8 o0 = *(const short8*)&qk[t0 + l16][q8];
    short8 o1 = *(const short8*)&qk[t0 + l16][32 + q8];
    short8 o2 = *(const short8*)&qk[t0 + l16][64 + q8];
#pragma unroll
    for (int nt = 0; nt < 6; nt++) {
        int i = nt * 16 + l16;
        if (nt < 5) {
            const short* w = projw_bf + ((nt + 1) * 16 + l16) * 96;
            wB0 = *(const short8*)&w[q8];
            wB1 = *(const short8*)&w[32 + q8];
            wB2 = *(const short8*)&w[64 + q8];
        }
        f32x4 acc = {0.f, 0.f, 0.f, 0.f};
        acc = MFMA(o0, wA0, acc);
        acc = MFMA(o1, wA1, acc);
        acc = MFMA(o2, wA2, acc);
        float pb = projb[i];
#pragma unroll
        for (int r = 0; r < 4; r++) {
            int t = t0 + q4 + r;
            if (t < 49) qk[t][i] = f2s(acc[r] + pb);
        }
        wA0 = wB0; wA1 = wB1; wA2 = wB2;
    }
    __syncthreads();                                 // [bar 4] proj out visible
#pragma unroll
    for (int k = 0; k < 3; k++) {
        int idx = tid + k * 256;
        if (idx < 588) {                             // 49*12
            int t = idx / 12, s = idx - t * 12;
            int r = t / 7, cc = t - r * 7;
            int hh = wh * 7 + r + 3;  if (hh >= D_H) hh -= D_H;
            int w2 = ww * 7 + cc + 3; if (w2 >= D_W) w2 -= D_W;
            *(short8*)&yt[((b * 224 + hh) * 224 + w2) * 96 + s * 8] =
                *(const short8*)&qk[t][s * 8];
        }
    }
}

// ---------------------------------------------------------------------------
// K2 (v8, measured-best): MLP, 64 tokens/block. Staged-wb with wb ALIASED over
//   dead xs region: LDS 33.8 KB -> 4 blocks/CU. Register-prefetch staging.
// ---------------------------------------------------------------------------
#define XCOL(row, c) ((((((c) >> 3) ^ (((row) >> 2) & 7)) << 3)) | ((c) & 7))

__global__ __launch_bounds__(256, 3) void k_mlp_t(
    const float* __restrict__ x, const short* __restrict__ ytk, float* __restrict__ y,
    const float* __restrict__ n2g, const float* __restrict__ n2b,
    const float* __restrict__ b1, const float* __restrict__ b2, const short* __restrict__ wsw)
{
    __shared__ __align__(16) char region[96 * 104 * 2];   // 19968 B: xs then wb
    short (*xs)[128] = (short(*)[128])region;             // 64*128*2 = 16384 <= 19968
    short (*wb)[104] = (short(*)[104])region;             // staged W chunk (96 rows)
    __shared__ __align__(16) short hb[64][104];           // GELU(H) chunk
    __shared__ float mean_s[64], rstd_s[64];

    const int tid  = threadIdx.x;
    const int wave = tid >> 6, lane = tid & 63;
    const int l16  = lane & 15, q8 = (lane >> 4) * 8, q4 = (lane >> 4) * 4;
    const int t0   = wave * 16;

    const short* w1_bf = wsw + WO_W1;
    const short* w2_bf = wsw + WO_W2;

    const int T0 = blockIdx.x * 64;
    const int b  = T0 / D_HW;
    const int p0 = T0 - b * D_HW;
    const int base = (b * 96) * D_HW + p0;

    // 1) attn tokens -> xs (coalesced global reads, chunk-swizzled LDS writes)
#pragma unroll
    for (int k = 0; k < 3; k++) {
        int idx = tid + k * 256;                     // < 768 = 64*12
        int t = idx / 12, s = idx - t * 12;
        *(short8*)&xs[t][(s ^ ((t >> 2) & 7)) << 3] =
            *(const short8*)&ytk[(T0 + t) * 96 + s * 8];
    }
    __syncthreads();                                 // [bar 1]

    // 2) compose y = x + attn: f32 in regs (24/thread), bf16 back into xs
    float yv[6][4];
#pragma unroll
    for (int k = 0; k < 6; k++) {
        int idx = tid + k * 256;                     // < 1536 = 96*16
        int c = idx >> 4, q = idx & 15;
        f32x4 xv = *(const f32x4*)&x[base + c * D_HW + q * 4];
        int ch = ((c >> 3) ^ (q & 7)) * 8 + (c & 7); // XCOL(q*4+j, c)
#pragma unroll
        for (int j = 0; j < 4; j++) {
            float v = xv[j] + s2f(xs[q * 4 + j][ch]);
            yv[k][j] = v;
            xs[q * 4 + j][ch] = f2s(v);
        }
    }
    __syncthreads();                                 // [bar 2]

    // 3) LN2 stats (4 lanes/token, own-wave rows)
    {
        int t = tid >> 2, p = tid & 3;
        float s = 0.f, s2 = 0.f;
#pragma unroll
        for (int i = 0; i < 6; i++) {
            int c = p * 24 + i * 4;
            s16x4 v4 = *(const s16x4*)&xs[t][XCOL(t, c)];
#pragma unroll
            for (int j = 0; j < 4; j++) { float v = s2f(v4[j]); s += v; s2 += v * v; }
        }
        s += __shfl_xor(s, 1); s2 += __shfl_xor(s2, 1);
        s += __shfl_xor(s, 2); s2 += __shfl_xor(s2, 2);
        if (p == 0) {
            float m = s * (1.f / 96.f);
            float var = s2 * (1.f / 96.f) - m * m;
            mean_s[t] = m; rstd_s[t] = rsqrtf(var + 1e-5f);
        }
    }

    // 4) hoist normalized A-frags (own rows, same-wave mean_s); xs dead after
    short8 xa[3];
    {
        int t = t0 + l16;
        float m = mean_s[t], rs = rstd_s[t];
        int key = (t >> 2) & 7;
#pragma unroll
        for (int kk = 0; kk < 3; kk++) {
            int ch = kk * 4 + (lane >> 4);
            xa[kk] = normfrag(&xs[t][(ch ^ key) << 3], n2g, n2b, ch * 8, m, rs);
        }
    }

    f32x4 c2[6];
#pragma unroll
    for (int nt = 0; nt < 6; nt++) c2[nt] = (f32x4){0.f, 0.f, 0.f, 0.f};

    // 5) 4 chunks; staging via register prefetch (issue early, write after bar)
    short8 pf[5];
#pragma unroll
    for (int k = 0; k < 5; k++) {
        int idx = tid + k * 256; if (idx > 1151) idx = 1151;
        pf[k] = *(const short8*)&w1_bf[idx * 8];
    }
#pragma unroll
    for (int jc = 0; jc < 4; jc++) {
        __syncthreads();   // jc=0: all xs reads done (wb aliases xs); jc>0: prev C2 wb reads done
        // write W1c
#pragma unroll
        for (int k = 0; k < 5; k++) {
            int idx = tid + k * 256;
            if (idx < 1152) { int j = idx / 12, s = idx - j * 12; *(short8*)&wb[j][s * 8] = pf[k]; }
        }
        __syncthreads();
        // issue W2c loads (consumed after next barrier)
#pragma unroll
        for (int k = 0; k < 5; k++) {
            int idx = tid + k * 256; if (idx > 1151) idx = 1151;
            int o = idx / 12, s = idx - o * 12;
            pf[k] = *(const short8*)&w2_bf[o * 384 + jc * 96 + s * 8];
        }
        // --- H = gelu(Xn W1c^T + b1) ---
#pragma unroll
        for (int nt = 0; nt < 6; nt++) {
            int jj = nt * 16 + l16;
            f32x4 acc = {0.f, 0.f, 0.f, 0.f};
            acc = MFMA(xa[0], *(const short8*)&wb[jj][q8],      acc);
            acc = MFMA(xa[1], *(const short8*)&wb[jj][32 + q8], acc);
            acc = MFMA(xa[2], *(const short8*)&wb[jj][64 + q8], acc);
            float bb = b1[jc * 96 + jj];
#pragma unroll
            for (int r = 0; r < 4; r++) {
                float v = acc[r] + bb;
                float g = 0.5f * v * (1.f + erf_fast(v * 0.7071067811865475f));
                hb[t0 + q4 + r][jj] = f2s(g);        // own rows
            }
        }
        __syncthreads();                             // all waves' W1c reads done
        // write W2c
#pragma unroll
        for (int k = 0; k < 5; k++) {
            int idx = tid + k * 256;
            if (idx < 1152) { int j = idx / 12, s = idx - j * 12; *(short8*)&wb[j][s * 8] = pf[k]; }
        }
        __syncthreads();
        // issue W1(jc+1) loads (consumed next iteration)
        if (jc < 3) {
#pragma unroll
            for (int k = 0; k < 5; k++) {
                int idx = tid + k * 256; if (idx > 1151) idx = 1151;
                pf[k] = *(const short8*)&w1_bf[(jc + 1) * 9216 + idx * 8];
            }
        }
        // --- C2 += H W2c^T (hb own rows) ---
        {
            short8 h0 = *(const short8*)&hb[t0 + l16][q8];
            short8 h1 = *(const short8*)&hb[t0 + l16][32 + q8];
            short8 h2 = *(const short8*)&hb[t0 + l16][64 + q8];
#pragma unroll
            for (int nt = 0; nt < 6; nt++) {
                int jj = nt * 16 + l16;
                c2[nt] = MFMA(h0, *(const short8*)&wb[jj][q8],      c2[nt]);
                c2[nt] = MFMA(h1, *(const short8*)&wb[jj][32 + q8], c2[nt]);
                c2[nt] = MFMA(h2, *(const short8*)&wb[jj][64 + q8], c2[nt]);
            }
        }
    }
    __syncthreads();       // [alias bar] last C2 wb reads done; xs may be written

    // 6) epilogue: mlp -> xs own rows (swizzled bf16), then out = yv + mlp
#pragma unroll
    for (int nt = 0; nt < 6; nt++) {
        int i = nt * 16 + l16;
        float bo = b2[i];
#pragma unroll
        for (int r = 0; r < 4; r++) {
            int t = t0 + q4 + r;
            xs[t][XCOL(t, i)] = f2s(bo + c2[nt][r]);
        }
    }
    __syncthreads();                                 // [bar 3]
#pragma unroll
    for (int k = 0; k < 6; k++) {
        int idx = tid + k * 256;
        int c = idx >> 4, q = idx & 15;
        int ch = ((c >> 3) ^ (q & 7)) * 8 + (c & 7);
        f32x4 o;
#pragma unroll
        for (int j = 0; j < 4; j++) o[j] = yv[k][j] + s2f(xs[q * 4 + j][ch]);
        *(f32x4*)&y[base + c * D_HW + q * 4] = o;
    }
}

// ===========================================================================
// FALLBACK PATH (used when ws_size < WS_NEED)
// ===========================================================================
__global__ __launch_bounds__(256, 3) void k_attn_f(
    const float* __restrict__ x, const float* __restrict__ n1g, const float* __restrict__ n1b,
    const float* __restrict__ qkvb, const float* __restrict__ relt,
    const float* __restrict__ projb, const short* __restrict__ wsw, float* __restrict__ y)
{
    __shared__ short qk[64][200];
    __shared__ short vt[96][72];
    __shared__ __align__(16) short xs[64][104];
    short (*ps)[72] = (short(*)[72])xs;
    __shared__ int   cnt_s[64];
    __shared__ float mean_s[64], rstd_s[64];

    const int tid  = threadIdx.x;
    const int wave = tid >> 6, lane = tid & 63;
    const int l16  = lane & 15, q8 = (lane >> 4) * 8, q4 = (lane >> 4) * 4;
    const int t0   = wave * 16;

    const short* qkvw_bf  = wsw + WO_QKVW;
    const short* projw_bf = wsw + WO_PROJW;

    const int wi = blockIdx.x;
    const int b  = wi >> 10, nw = wi & 1023;
    const int wh = nw >> 5, ww = nw & 31;
    const bool edge = (wh == 31) || (ww == 31);

    if (tid < 64) {
        int t = (tid < 49) ? tid : 48;
        int r = t / 7, c = t - r * 7;
        int sh = wh * 7 + r, sw = ww * 7 + c;
        int rh = (sh < 217) ? 0 : ((sh < 221) ? 1 : 2);
        int rw = (sw < 217) ? 0 : ((sw < 221) ? 1 : 2);
        cnt_s[tid] = rh * 3 + rw;
    }
    {
        int t = lane;
        int r = t / 7, cc = t - r * 7;
        int hh = wh * 7 + r + 3;  if (hh >= D_H) hh -= D_H;
        int w2 = ww * 7 + cc + 3; if (w2 >= D_W) w2 -= D_W;
        int off0 = (b * 96) * D_HW + hh * D_W + w2;
#pragma unroll
        for (int n = 0; n < 6; n++) {
            int c0 = wave * 24 + n * 4;
            s16x4 v4 = {0, 0, 0, 0};
            if (t < 49) {
                v4[0] = f2s(x[off0 + (c0 + 0) * D_HW]);
                v4[1] = f2s(x[off0 + (c0 + 1) * D_HW]);
                v4[2] = f2s(x[off0 + (c0 + 2) * D_HW]);
                v4[3] = f2s(x[off0 + (c0 + 3) * D_HW]);
            }
            *(s16x4*)&xs[t][c0] = v4;
        }
    }
    __syncthreads();
    {
        int t = tid >> 2, p = tid & 3;
        float s = 0.f, s2 = 0.f;
#pragma unroll
        for (int i = 0; i < 6; i++) {
            s16x4 v4 = *(const s16x4*)&xs[t][p * 24 + i * 4];
#pragma unroll
            for (int j = 0; j < 4; j++) { float v = s2f(v4[j]); s += v; s2 += v * v; }
        }
        s += __shfl_xor(s, 1); s2 += __shfl_xor(s2, 1);
        s += __shfl_xor(s, 2); s2 += __shfl_xor(s2, 2);
        if (p == 0) {
            float m = s * (1.f / 96.f);
            float var = s2 * (1.f / 96.f) - m * m;
            mean_s[t] = m; rstd_s[t] = rsqrtf(var + 1e-5f);
        }
    }
    __syncthreads();

    const float m0 = mean_s[t0 + l16], rs0 = rstd_s[t0 + l16];
    short8 a0 = normfrag(&xs[t0 + l16][q8],      n1g, n1b, q8,      m0, rs0);
    short8 a1 = normfrag(&xs[t0 + l16][32 + q8], n1g, n1b, 32 + q8, m0, rs0);
    short8 a2 = normfrag(&xs[t0 + l16][64 + q8], n1g, n1b, 64 + q8, m0, rs0);

#pragma unroll
    for (int jc = 0; jc < 3; jc++) {
#pragma unroll
        for (int nt = 0; nt < 6; nt++) {
            int jj = nt * 16 + l16;
            const short* wr = qkvw_bf + (jc * 96 + jj) * 96;
            f32x4 acc = {0.f, 0.f, 0.f, 0.f};
            acc = MFMA(a0, *(const short8*)&wr[q8],      acc);
            acc = MFMA(a1, *(const short8*)&wr[32 + q8], acc);
            acc = MFMA(a2, *(const short8*)&wr[64 + q8], acc);
            float bias = qkvb[jc * 96 + jj];
            if (jc == 0) {
#pragma unroll
                for (int r = 0; r < 4; r++) qk[t0 + q4 + r][jj] = f2s((acc[r] + bias) * SCALE);
            } else if (jc == 1) {
#pragma unroll
                for (int r = 0; r < 4; r++) qk[t0 + q4 + r][96 + jj] = f2s(acc[r] + bias);
            } else {
                s16x4 v4;
#pragma unroll
                for (int r = 0; r < 4; r++) v4[r] = f2s(acc[r] + bias);
                *(s16x4*)&vt[jj][t0 + q4] = v4;
            }
        }
    }

    float biasv[4][4][3];
#pragma unroll
    for (int nt = 0; nt < 4; nt++) {
        int m  = nt * 16 + l16;
        int mm = (m < 49) ? m : 48;
        int r2 = mm / 7, c2 = mm - r2 * 7;
        int cm = cnt_s[m];
#pragma unroll
        for (int r = 0; r < 4; r++) {
            int n  = t0 + q4 + r;
            int nn = (n < 49) ? n : 48;
            int r1 = nn / 7, c1 = nn - r1 * 7;
            int ri = ((r1 - r2 + 6) * 13 + (c1 - c2 + 6)) * 3;
            float mk = (edge && (cnt_s[n] != cm)) ? -100.f : 0.f;
            biasv[nt][r][0] = relt[ri + 0] + mk;
            biasv[nt][r][1] = relt[ri + 1] + mk;
            biasv[nt][r][2] = relt[ri + 2] + mk;
        }
    }
    const bool inval3 = (l16 != 0);

#pragma unroll
    for (int h = 0; h < 3; h++) {
        __syncthreads();
        short8 aq = *(const short8*)&qk[t0 + l16][h * 32 + q8];
        f32x4 sv[4];
#pragma unroll
        for (int nt = 0; nt < 4; nt++) {
            f32x4 z = {0.f, 0.f, 0.f, 0.f};
            sv[nt] = MFMA(aq, *(const short8*)&qk[nt * 16 + l16][96 + h * 32 + q8], z);
        }
        float mx[4] = {-1e30f, -1e30f, -1e30f, -1e30f};
#pragma unroll
        for (int nt = 0; nt < 4; nt++) {
#pragma unroll
            for (int r = 0; r < 4; r++) {
                float v = sv[nt][r] + biasv[nt][r][h];
                if (nt == 3 && inval3) v = -1e30f;
                sv[nt][r] = v;
                mx[r] = fmaxf(mx[r], v);
            }
        }
#pragma unroll
        for (int d = 1; d < 16; d <<= 1) {
#pragma unroll
            for (int r = 0; r < 4; r++) mx[r] = fmaxf(mx[r], __shfl_xor(mx[r], d));
        }
        float sm[4] = {0.f, 0.f, 0.f, 0.f};
#pragma unroll
        for (int nt = 0; nt < 4; nt++) {
#pragma unroll
            for (int r = 0; r < 4; r++) {
                float e = (nt == 3 && inval3) ? 0.f : __expf(sv[nt][r] - mx[r]);
                sv[nt][r] = e;
                sm[r] += e;
            }
        }
#pragma unroll
        for (int d = 1; d < 16; d <<= 1) {
#pragma unroll
            for (int r = 0; r < 4; r++) sm[r] += __shfl_xor(sm[r], d);
        }
        float inv[4];
#pragma unroll
        for (int r = 0; r < 4; r++) inv[r] = 1.f / sm[r];
#pragma unroll
        for (int nt = 0; nt < 4; nt++) {
#pragma unroll
            for (int r = 0; r < 4; r++)
                ps[t0 + q4 + r][nt * 16 + l16] = f2s(sv[nt][r] * inv[r]);
        }
        __syncthreads();
        short8 p0 = *(const short8*)&ps[t0 + l16][q8];
        short8 p1 = *(const short8*)&ps[t0 + l16][32 + q8];
#pragma unroll
        for (int nt = 0; nt < 2; nt++) {
            f32x4 acc = {0.f, 0.f, 0.f, 0.f};
            acc = MFMA(p0, *(const short8*)&vt[h * 32 + nt * 16 + l16][q8],      acc);
            acc = MFMA(p1, *(const short8*)&vt[h * 32 + nt * 16 + l16][32 + q8], acc);
            int d = nt * 16 + l16;
#pragma unroll
            for (int r = 0; r < 4; r++) {
                int t = t0 + q4 + r;
                if (t < 49) qk[t][h * 32 + d] = f2s(acc[r]);
            }
        }
    }

    __syncthreads();
    short8 o0 = *(const short8*)&qk[t0 + l16][q8];
    short8 o1 = *(const short8*)&qk[t0 + l16][32 + q8];
    short8 o2 = *(const short8*)&qk[t0 + l16][64 + q8];
    int  po[4];
    bool tv[4];
#pragma unroll
    for (int r = 0; r < 4; r++) {
        int t = t0 + q4 + r;
        tv[r] = (t < 49);
        int tt = tv[r] ? t : 0;
        int rr = tt / 7, cc = tt - rr * 7;
        int hh = wh * 7 + rr + 3;  if (hh >= D_H) hh -= D_H;
        int w2 = ww * 7 + cc + 3;  if (w2 >= D_W) w2 -= D_W;
        po[r] = (b * 96) * D_HW + hh * D_W + w2;
    }
#pragma unroll
    for (int nt = 0; nt < 6; nt++) {
        int i = nt * 16 + l16;
        const short* wr = projw_bf + i * 96;
        f32x4 acc = {0.f, 0.f, 0.f, 0.f};
        acc = MFMA(o0, *(const short8*)&wr[q8],      acc);
        acc = MFMA(o1, *(const short8*)&wr[32 + q8], acc);
        acc = MFMA(o2, *(const short8*)&wr[64 + q8], acc);
        float pb = projb[i];
#pragma unroll
        for (int r = 0; r < 4; r++) {
            if (tv[r]) {
                int off = po[r] + i * D_HW;
                y[off] = x[off] + acc[r] + pb;
            }
        }
    }
}

__global__ __launch_bounds__(256, 3) void k_mlp_f(
    float* __restrict__ y, const float* __restrict__ n2g, const float* __restrict__ n2b,
    const float* __restrict__ b1, const float* __restrict__ b2, const short* __restrict__ wsw)
{
    __shared__ short xs[128][104];
    __shared__ short hb[128][104];
    __shared__ float mean_s[128], rstd_s[128];

    const int tid  = threadIdx.x;
    const int wave = tid >> 6, lane = tid & 63;
    const int l16  = lane & 15, q8 = (lane >> 4) * 8, q4 = (lane >> 4) * 4;
    const int t0   = wave * 32;

    const short* w1_bf = wsw + WO_W1;
    const short* w2_bf = wsw + WO_W2;

    const int T0 = blockIdx.x * 128;
    const int b  = T0 / D_HW;
    const int p0 = T0 - b * D_HW;
    const int base = (b * 96) * D_HW + p0;

    for (int idx = tid; idx < 96 * 32; idx += 256) {
        int c = idx >> 5, q = idx & 31;
        f32x4 v4 = *(const f32x4*)&y[base + c * D_HW + q * 4];
        xs[q * 4 + 0][c] = f2s(v4[0]);
        xs[q * 4 + 1][c] = f2s(v4[1]);
        xs[q * 4 + 2][c] = f2s(v4[2]);
        xs[q * 4 + 3][c] = f2s(v4[3]);
    }
    __syncthreads();
    {
        int t = tid >> 1, p = tid & 1;
        float s = 0.f, s2 = 0.f;
#pragma unroll
        for (int i = 0; i < 12; i++) {
            s16x4 v4 = *(const s16x4*)&xs[t][p * 48 + i * 4];
#pragma unroll
            for (int j = 0; j < 4; j++) { float v = s2f(v4[j]); s += v; s2 += v * v; }
        }
        s += __shfl_xor(s, 1); s2 += __shfl_xor(s2, 1);
        float m = s * (1.f / 96.f);
        float var = s2 * (1.f / 96.f) - m * m;
        mean_s[t] = m; rstd_s[t] = rsqrtf(var + 1e-5f);
    }
    __syncthreads();

    short8 xa[2][3];
#pragma unroll
    for (int s = 0; s < 2; s++) {
        float m = mean_s[t0 + s * 16 + l16], rs = rstd_s[t0 + s * 16 + l16];
#pragma unroll
        for (int kk = 0; kk < 3; kk++)
            xa[s][kk] = normfrag(&xs[t0 + s * 16 + l16][kk * 32 + q8], n2g, n2b,
                                 kk * 32 + q8, m, rs);
    }

    f32x4 c2[2][6];
#pragma unroll
    for (int s = 0; s < 2; s++)
#pragma unroll
        for (int nt = 0; nt < 6; nt++) c2[s][nt] = (f32x4){0.f, 0.f, 0.f, 0.f};

    for (int jc = 0; jc < 4; jc++) {
#pragma unroll
        for (int s = 0; s < 2; s++) {
#pragma unroll
            for (int nt = 0; nt < 6; nt++) {
                int jj = nt * 16 + l16;
                const short* wr = w1_bf + (jc * 96 + jj) * 96;
                f32x4 acc = {0.f, 0.f, 0.f, 0.f};
                acc = MFMA(xa[s][0], *(const short8*)&wr[q8],      acc);
                acc = MFMA(xa[s][1], *(const short8*)&wr[32 + q8], acc);
                acc = MFMA(xa[s][2], *(const short8*)&wr[64 + q8], acc);
                float bb = b1[jc * 96 + jj];
#pragma unroll
                for (int r = 0; r < 4; r++) {
                    float v = acc[r] + bb;
                    float g = 0.5f * v * (1.f + erf_fast(v * 0.7071067811865475f));
                    hb[t0 + s * 16 + q4 + r][jj] = f2s(g);
                }
            }
        }
        __syncthreads();
#pragma unroll
        for (int s = 0; s < 2; s++) {
            short8 h0 = *(const short8*)&hb[t0 + s * 16 + l16][q8];
            short8 h1 = *(const short8*)&hb[t0 + s * 16 + l16][32 + q8];
            short8 h2 = *(const short8*)&hb[t0 + s * 16 + l16][64 + q8];
#pragma unroll
            for (int nt = 0; nt < 6; nt++) {
                const short* wr = w2_bf + (nt * 16 + l16) * 384 + jc * 96;
                c2[s][nt] = MFMA(h0, *(const short8*)&wr[q8],      c2[s][nt]);
                c2[s][nt] = MFMA(h1, *(const short8*)&wr[32 + q8], c2[s][nt]);
                c2[s][nt] = MFMA(h2, *(const short8*)&wr[64 + q8], c2[s][nt]);
            }
        }
        __syncthreads();
    }

#pragma unroll
    for (int s = 0; s < 2; s++)
#pragma unroll
        for (int nt = 0; nt < 6; nt++) {
            int i = nt * 16 + l16;
            float bo = b2[i];
#pragma unroll
            for (int r = 0; r < 4; r++)
                xs[t0 + s * 16 + q4 + r][i] = f2s(bo + c2[s][nt][r]);
        }
    __syncthreads();
    for (int idx = tid; idx < 96 * 32; idx += 256) {
        int c = idx >> 5, q = idx & 31;
        int off = base + c * D_HW + q * 4;
        f32x4 v4 = *(const f32x4*)&y[off];
        v4[0] += s2f(xs[q * 4 + 0][c]);
        v4[1] += s2f(xs[q * 4 + 1][c]);
        v4[2] += s2f(xs[q * 4 + 2][c]);
        v4[3] += s2f(xs[q * 4 + 3][c]);
        *(f32x4*)&y[off] = v4;
    }
}

extern "C" void kernel_launch(void* const* d_in, const int* in_sizes, int n_in,
                              void* d_out, int out_size, void* d_ws, size_t ws_size,
                              hipStream_t stream) {
    const float* x    = (const float*)d_in[0];
    const float* n1g  = (const float*)d_in[1];
    const float* n1b  = (const float*)d_in[2];
    const float* qkvw = (const float*)d_in[3];
    const float* qkvb = (const float*)d_in[4];
    const float* relt = (const float*)d_in[5];
    const float* projw= (const float*)d_in[6];
    const float* projb= (const float*)d_in[7];
    const float* n2g  = (const float*)d_in[8];
    const float* n2b  = (const float*)d_in[9];
    const float* w1   = (const float*)d_in[10];
    const float* b1   = (const float*)d_in[11];
    const float* w2   = (const float*)d_in[12];
    const float* b2   = (const float*)d_in[13];
    float* y  = (float*)d_out;
    short* ws = (short*)d_ws;

    if (ws_size >= WS_NEED) {
        short* xt  = ws + XT_SH;
        short* ytk = ws + YT_SH;
        short* wbf = ws + W_SH;
        float* tabf = (float*)(ws + TAB_SH);
        k_prep<<<124, 256, 0, stream>>>(qkvw, projw, w1, w2, relt, wbf, tabf);
        k_t<<<1792, 256, 0, stream>>>(x, xt);
        k_attn_t<<<8192, 256, 0, stream>>>(xt, n1g, n1b, qkvb, tabf, projb, wbf, ytk);
        k_mlp_t<<<6272, 256, 0, stream>>>(x, ytk, y, n2g, n2b, b1, b2, wbf);
    } else {
        k_prep<<<108, 256, 0, stream>>>(qkvw, projw, w1, w2, relt, ws, (float*)ws);
        k_attn_f<<<8192, 256, 0, stream>>>(x, n1g, n1b, qkvb, relt, projb, ws, y);
        k_mlp_f<<<3136, 256, 0, stream>>>(y, n2g, n2b, b1, b2, ws);
    }
}

// Round 10
// 631.965 us; speedup vs baseline: 1.0711x; 1.0711x over previous
//
#include <hip/hip_runtime.h>
#include <hip/hip_bf16.h>

typedef __attribute__((ext_vector_type(8))) short short8;
typedef __attribute__((ext_vector_type(4))) short s16x4;
typedef __attribute__((ext_vector_type(4))) float f32x4;

#define D_H   224
#define D_W   224
#define D_HW  50176
#define SCALE 0.17677669529663687f  // 32^-0.5

// weight sub-offsets (shorts, relative to weight base)
#define WO_QKVW  0        // 27648
#define WO_PROJW 27648    // 9216
#define WO_W1    36864    // 36864
#define WO_W2    73728    // 36864
#define WO_TOT   110592

// big-workspace layout (shorts)
#define XT_SH 0                       // 8*224*224*96 = 38535168 bf16 (LN1-normalized)
#define YT_SH 38535168                // same size
#define W_SH  77070336                // weights
#define WS_NEED ((size_t)(77070336 + 110592) * 2)   // 154,361,856 B

static __device__ __forceinline__ short f2s(float v) {
    union { __hip_bfloat16 b; short s; } u; u.b = __float2bfloat16(v); return u.s;
}
static __device__ __forceinline__ float s2f(short s) {
    union { short s; __hip_bfloat16 b; } u; u.s = s; return __bfloat162float(u.b);
}

#define MFMA(a, b, c) __builtin_amdgcn_mfma_f32_16x16x32_bf16((a), (b), (c), 0, 0, 0)

static __device__ __forceinline__ short8 normfrag(const short* p, const float* g,
                                                  const float* b, int c0, float m, float rs) {
    short8 r = *(const short8*)p;
    short8 o;
#pragma unroll
    for (int j = 0; j < 8; j++) o[j] = f2s((s2f(r[j]) - m) * rs * g[c0 + j] + b[c0 + j]);
    return o;
}

// A&S 7.1.26 erf approximation: max abs err ~1.5e-7 (result stored to bf16 anyway)
static __device__ __forceinline__ float erf_fast(float x) {
    float a = fabsf(x);
    float t = __builtin_amdgcn_rcpf(1.f + 0.3275911f * a);
    float p = t * (0.254829592f + t * (-0.284496736f + t * (1.421413741f +
              t * (-1.453152027f + t * 1.061405429f))));
    float y = 1.f - p * __expf(-a * a);
    return copysignf(y, x);
}

// ---------------------------------------------------------------------------
// K0: one-shot f32 -> bf16 weight conversion (into given base)
// ---------------------------------------------------------------------------
__global__ __launch_bounds__(256) void k_prep(
    const float* __restrict__ qkvw, const float* __restrict__ projw,
    const float* __restrict__ w1, const float* __restrict__ w2, short* __restrict__ ws)
{
    int i4 = blockIdx.x * 256 + threadIdx.x;         // 27648 f32x4 groups total
    const float* src; int off;
    if (i4 < 6912)        { src = qkvw;  off = 0; }
    else if (i4 < 9216)   { src = projw; off = 6912; }
    else if (i4 < 18432)  { src = w1;    off = 9216; }
    else                  { src = w2;    off = 18432; }
    f32x4 v = *(const f32x4*)&src[(i4 - off) * 4];
    s16x4 s;
#pragma unroll
    for (int j = 0; j < 4; j++) s[j] = f2s(v[j]);
    *(s16x4*)&ws[i4 * 4] = s;
}

// ---------------------------------------------------------------------------
// KT (v4): x (B,C,H,W) f32 -> xt (B,H,W,C) bf16, WITH LayerNorm1 FUSED.
//   Phase 1: in-register 4x4 micro-transpose (4x f32x4 coalesced loads) into
//            XOR-swizzled [224][128] tile.
//   Phase 2a: LN stats, 1 thread/token (24 s16x4 LDS reads).
//   Phase 2b: normalize fused into the coalesced short8 streamout.
//   xt holds NORMALIZED tokens -> k_attn drops its whole LN phase.
// ---------------------------------------------------------------------------
__global__ __launch_bounds__(256) void k_t(
    const float* __restrict__ x, const float* __restrict__ n1g,
    const float* __restrict__ n1b, short* __restrict__ xt)
{
    __shared__ short tile[224][128];     // 57344 B; 32 slots x 4 shorts per row
    __shared__ float mean_s[224], rstd_s[224];
    const int tid = threadIdx.x;
    const int bh = blockIdx.x;
    const int b = bh / 224, h = bh - b * 224;
    const int pbase = (b * 96) * D_HW + h * 224;

#pragma unroll
    for (int k = 0; k < 6; k++) {
        int idx = tid + k * 256;         // valid < 1344 = 24 c-quads * 56 w-quads
        if (idx < 1344) {
            int c4 = idx / 56, w4 = idx - c4 * 56;
            float vv[4][4];
#pragma unroll
            for (int j = 0; j < 4; j++) {
                f32x4 v = *(const f32x4*)&x[pbase + (c4 * 4 + j) * D_HW + w4 * 4];
#pragma unroll
                for (int i = 0; i < 4; i++) vv[j][i] = v[i];
            }
#pragma unroll
            for (int i = 0; i < 4; i++) {
                int w = w4 * 4 + i;
                s16x4 o;
#pragma unroll
                for (int j = 0; j < 4; j++) o[j] = f2s(vv[j][i]);
                *(s16x4*)&tile[w][(c4 ^ (w & 31)) * 4] = o;
            }
        }
    }
    __syncthreads();
    // ---- LN1 stats: one thread per token ----
    if (tid < 224) {
        int key = tid & 31;
        float s = 0.f, s2 = 0.f;
#pragma unroll
        for (int c4 = 0; c4 < 24; c4++) {
            s16x4 v4 = *(const s16x4*)&tile[tid][(c4 ^ key) << 2];
#pragma unroll
            for (int j = 0; j < 4; j++) { float v = s2f(v4[j]); s += v; s2 += v * v; }
        }
        float m = s * (1.f / 96.f);
        float var = s2 * (1.f / 96.f) - m * m;
        mean_s[tid] = m; rstd_s[tid] = rsqrtf(var + 1e-5f);
    }
    __syncthreads();
    // ---- normalize + coalesced streamout ----
    const int obase = ((b * 224 + h) * 224) * 96;
#pragma unroll
    for (int k = 0; k < 11; k++) {
        int idx = tid + k * 256;         // valid < 2688 = 224*12
        if (idx < 2688) {
            int w = idx / 12, s = idx - w * 12;
            int kk = w & 31;
            s16x4 a = *(const s16x4*)&tile[w][((2 * s) ^ kk) << 2];
            s16x4 c = *(const s16x4*)&tile[w][((2 * s + 1) ^ kk) << 2];
            float m = mean_s[w], rs = rstd_s[w];
            f32x4 g0 = *(const f32x4*)&n1g[s * 8];
            f32x4 g1 = *(const f32x4*)&n1g[s * 8 + 4];
            f32x4 b0 = *(const f32x4*)&n1b[s * 8];
            f32x4 b1 = *(const f32x4*)&n1b[s * 8 + 4];
            short8 o;
#pragma unroll
            for (int j = 0; j < 4; j++) o[j]     = f2s((s2f(a[j]) - m) * rs * g0[j] + b0[j]);
#pragma unroll
            for (int j = 0; j < 4; j++) o[4 + j] = f2s((s2f(c[j]) - m) * rs * g1[j] + b1[j]);
            *(short8*)&xt[obase + w * 96 + s * 8] = o;
        }
    }
}

// ---------------------------------------------------------------------------
// K1 (v8): one block per window, token-major NORMALIZED bf16 in, bf16 out.
//   No LN phase (xt pre-normalized). 4 barriers; 2-deep register prefetch of
//   direct-global W frags; r8 in-register biasv (VALU, overlaps prefetch).
// ---------------------------------------------------------------------------
__global__ __launch_bounds__(256, 3) void k_attn_t(
    const short* __restrict__ xt, const float* __restrict__ qkvb,
    const float* __restrict__ relt, const float* __restrict__ projb,
    const short* __restrict__ wsw, short* __restrict__ yt)
{
    __shared__ short qk[64][200];                    // Q(0..95 pre-scaled) K(96..191); PV/proj out
    __shared__ __align__(16) short region[11520];    // [ps 4608][vt 6912] shorts
    short (*xs)[104] = (short(*)[104])region;        // normalized tokens, pre-QKV only
    short (*ps)[72]  = (short(*)[72])region;         // P matrix (heads phase)
    short (*vt)[72]  = (short(*)[72])(region + 4608);// V d-major (96 rows x 72)
    __shared__ int   cnt_s[64];

    const int tid  = threadIdx.x;
    const int wave = tid >> 6, lane = tid & 63;
    const int l16  = lane & 15, q8 = (lane >> 4) * 8, q4 = (lane >> 4) * 4;
    const int t0   = wave * 16;

    const short* qkvw_bf  = wsw + WO_QKVW;
    const short* projw_bf = wsw + WO_PROJW;

    const int wi = blockIdx.x;
    const int b  = wi >> 10, nw = wi & 1023;
    const int wh = nw >> 5, ww = nw & 31;
    const bool edge = (wh == 31) || (ww == 31);

    if (tid < 64) {
        int t = (tid < 49) ? tid : 48;
        int r = t / 7, c = t - r * 7;
        int sh = wh * 7 + r, sw = ww * 7 + c;
        int rh = (sh < 217) ? 0 : ((sh < 221) ? 1 : 2);
        int rw = (sw < 217) ? 0 : ((sw < 221) ? 1 : 2);
        cnt_s[tid] = rh * 3 + rw;
    }
    // ---- gather: 64 tokens x 12 16B-segments from xt (already normalized) ----
#pragma unroll
    for (int k = 0; k < 3; k++) {
        int idx = tid + k * 256;                     // < 768 = 64*12
        int t = idx / 12, s = idx - t * 12;
        short8 v = {0, 0, 0, 0, 0, 0, 0, 0};
        if (t < 49) {
            int r = t / 7, cc = t - r * 7;
            int hh = wh * 7 + r + 3;  if (hh >= D_H) hh -= D_H;
            int w2 = ww * 7 + cc + 3; if (w2 >= D_W) w2 -= D_W;
            v = *(const short8*)&xt[((b * 224 + hh) * 224 + w2) * 96 + s * 8];
        }
        *(short8*)&xs[t][s * 8] = v;
    }
    __syncthreads();                                 // [bar 1] xs + cnt_s visible

    // ---- A-frags: plain vector loads (normalization already applied) ----
    short8 a0 = *(const short8*)&xs[t0 + l16][q8];
    short8 a1 = *(const short8*)&xs[t0 + l16][32 + q8];
    short8 a2 = *(const short8*)&xs[t0 + l16][64 + q8];

    // issue first QKV W-group loads early (hide under barrier drain)
    short8 wA0, wA1, wA2, wB0, wB1, wB2;
    {
        const short* w = qkvw_bf + l16 * 96;         // g=0: jc=0, nt=0
        wA0 = *(const short8*)&w[q8];
        wA1 = *(const short8*)&w[32 + q8];
        wA2 = *(const short8*)&w[64 + q8];
    }
    __syncthreads();                                 // [bar 2] all xs reads done (vt overwrites)

    // ---- QKV: 18 groups, 2-deep register-pipelined W loads ----
#pragma unroll
    for (int g = 0; g < 18; g++) {
        const int jc = g / 6, nt = g - jc * 6;
        const int jj = nt * 16 + l16;
        if (g < 17) {
            int g2 = g + 1, jc2 = g2 / 6, nt2 = g2 - jc2 * 6;
            const short* w = qkvw_bf + (jc2 * 96 + nt2 * 16 + l16) * 96;
            wB0 = *(const short8*)&w[q8];
            wB1 = *(const short8*)&w[32 + q8];
            wB2 = *(const short8*)&w[64 + q8];
        }
        f32x4 acc = {0.f, 0.f, 0.f, 0.f};
        acc = MFMA(a0, wA0, acc);
        acc = MFMA(a1, wA1, acc);
        acc = MFMA(a2, wA2, acc);
        float bias = qkvb[jc * 96 + jj];
        if (jc == 0) {
#pragma unroll
            for (int r = 0; r < 4; r++) qk[t0 + q4 + r][jj] = f2s((acc[r] + bias) * SCALE);
        } else if (jc == 1) {
#pragma unroll
            for (int r = 0; r < 4; r++) qk[t0 + q4 + r][96 + jj] = f2s(acc[r] + bias);
        } else {
            s16x4 v4;
#pragma unroll
            for (int r = 0; r < 4; r++) v4[r] = f2s(acc[r] + bias);
            *(s16x4*)&vt[jj][t0 + q4] = v4;
        }
        wA0 = wB0; wA1 = wB1; wA2 = wB2;
    }

    // ---- per-lane rel-pos bias + mask in registers (VALU, overlaps pipeline) ----
    float biasv[4][4][3];
#pragma unroll
    for (int nt = 0; nt < 4; nt++) {
        int m  = nt * 16 + l16;
        int mm = (m < 49) ? m : 48;
        int r2 = mm / 7, c2 = mm - r2 * 7;
        int cm = cnt_s[m];
#pragma unroll
        for (int r = 0; r < 4; r++) {
            int n  = t0 + q4 + r;
            int nn = (n < 49) ? n : 48;
            int r1 = nn / 7, c1 = nn - r1 * 7;
            int ri = ((r1 - r2 + 6) * 13 + (c1 - c2 + 6)) * 3;
            float mk = (edge && (cnt_s[n] != cm)) ? -100.f : 0.f;
            biasv[nt][r][0] = relt[ri + 0] + mk;
            biasv[nt][r][1] = relt[ri + 1] + mk;
            biasv[nt][r][2] = relt[ri + 2] + mk;
        }
    }
    const bool inval3 = (l16 != 0);

    __syncthreads();                                 // [bar 3] K + V visible to all waves

    // ---- attention heads: zero internal barriers ----
#pragma unroll
    for (int h = 0; h < 3; h++) {
        short8 aq = *(const short8*)&qk[t0 + l16][h * 32 + q8];  // own rows
        f32x4 sv[4];
#pragma unroll
        for (int nt = 0; nt < 4; nt++) {
            f32x4 z = {0.f, 0.f, 0.f, 0.f};
            sv[nt] = MFMA(aq, *(const short8*)&qk[nt * 16 + l16][96 + h * 32 + q8], z);
        }
        float mx[4] = {-1e30f, -1e30f, -1e30f, -1e30f};
#pragma unroll
        for (int nt = 0; nt < 4; nt++) {
#pragma unroll
            for (int r = 0; r < 4; r++) {
                float v = sv[nt][r] + biasv[nt][r][h];
                if (nt == 3 && inval3) v = -1e30f;
                sv[nt][r] = v;
                mx[r] = fmaxf(mx[r], v);
            }
        }
#pragma unroll
        for (int d = 1; d < 16; d <<= 1) {
#pragma unroll
            for (int r = 0; r < 4; r++) mx[r] = fmaxf(mx[r], __shfl_xor(mx[r], d));
        }
        float sm[4] = {0.f, 0.f, 0.f, 0.f};
#pragma unroll
        for (int nt = 0; nt < 4; nt++) {
#pragma unroll
            for (int r = 0; r < 4; r++) {
                float e = (nt == 3 && inval3) ? 0.f : __expf(sv[nt][r] - mx[r]);
                sv[nt][r] = e;
                sm[r] += e;
            }
        }
#pragma unroll
        for (int d = 1; d < 16; d <<= 1) {
#pragma unroll
            for (int r = 0; r < 4; r++) sm[r] += __shfl_xor(sm[r], d);
        }
        float inv[4];
#pragma unroll
        for (int r = 0; r < 4; r++) inv[r] = __builtin_amdgcn_rcpf(sm[r]);
#pragma unroll
        for (int nt = 0; nt < 4; nt++) {
#pragma unroll
            for (int r = 0; r < 4; r++)
                ps[t0 + q4 + r][nt * 16 + l16] = f2s(sv[nt][r] * inv[r]);   // own rows
        }
        short8 p0 = *(const short8*)&ps[t0 + l16][q8];
        short8 p1 = *(const short8*)&ps[t0 + l16][32 + q8];
#pragma unroll
        for (int nt = 0; nt < 2; nt++) {
            f32x4 acc = {0.f, 0.f, 0.f, 0.f};
            acc = MFMA(p0, *(const short8*)&vt[h * 32 + nt * 16 + l16][q8],      acc);
            acc = MFMA(p1, *(const short8*)&vt[h * 32 + nt * 16 + l16][32 + q8], acc);
            int d = nt * 16 + l16;
#pragma unroll
            for (int r = 0; r < 4; r++) {
                int t = t0 + q4 + r;
                if (t < 49) qk[t][h * 32 + d] = f2s(acc[r]);                // own rows
            }
        }
    }

    // ---- proj: 6 groups, 2-deep register-pipelined W loads ----
    {
        const short* w = projw_bf + l16 * 96;        // g=0
        wA0 = *(const short8*)&w[q8];
        wA1 = *(const short8*)&w[32 + q8];
        wA2 = *(const short8*)&w[64 + q8];
    }
    short8 o0 = *(const short8*)&qk[t0 + l16][q8];
    short8 o1 = *(const short8*)&qk[t0 + l16][32 + q8];
    short8 o2 = *(const short8*)&qk[t0 + l16][64 + q8];
#pragma unroll
    for (int nt = 0; nt < 6; nt++) {
        int i = nt * 16 + l16;
        if (nt < 5) {
            const short* w = projw_bf + ((nt + 1) * 16 + l16) * 96;
            wB0 = *(const short8*)&w[q8];
            wB1 = *(const short8*)&w[32 + q8];
            wB2 = *(const short8*)&w[64 + q8];
        }
        f32x4 acc = {0.f, 0.f, 0.f, 0.f};
        acc = MFMA(o0, wA0, acc);
        acc = MFMA(o1, wA1, acc);
        acc = MFMA(o2, wA2, acc);
        float pb = projb[i];
#pragma unroll
        for (int r = 0; r < 4; r++) {
            int t = t0 + q4 + r;
            if (t < 49) qk[t][i] = f2s(acc[r] + pb);
        }
        wA0 = wB0; wA1 = wB1; wA2 = wB2;
    }
    __syncthreads();                                 // [bar 4] proj out visible
#pragma unroll
    for (int k = 0; k < 3; k++) {
        int idx = tid + k * 256;
        if (idx < 588) {                             // 49*12
            int t = idx / 12, s = idx - t * 12;
            int r = t / 7, cc = t - r * 7;
            int hh = wh * 7 + r + 3;  if (hh >= D_H) hh -= D_H;
            int w2 = ww * 7 + cc + 3; if (w2 >= D_W) w2 -= D_W;
            *(short8*)&yt[((b * 224 + hh) * 224 + w2) * 96 + s * 8] =
                *(const short8*)&qk[t][s * 8];
        }
    }
}

// ---------------------------------------------------------------------------
// K2 (v8, measured-best): MLP, 64 tokens/block. Staged-wb with wb ALIASED over
//   dead xs region: LDS 33.8 KB -> 4 blocks/CU. Register-prefetch staging.
// ---------------------------------------------------------------------------
#define XCOL(row, c) ((((((c) >> 3) ^ (((row) >> 2) & 7)) << 3)) | ((c) & 7))

__global__ __launch_bounds__(256, 3) void k_mlp_t(
    const float* __restrict__ x, const short* __restrict__ ytk, float* __restrict__ y,
    const float* __restrict__ n2g, const float* __restrict__ n2b,
    const float* __restrict__ b1, const float* __restrict__ b2, const short* __restrict__ wsw)
{
    __shared__ __align__(16) char region[96 * 104 * 2];   // 19968 B: xs then wb
    short (*xs)[128] = (short(*)[128])region;             // 64*128*2 = 16384 <= 19968
    short (*wb)[104] = (short(*)[104])region;             // staged W chunk (96 rows)
    __shared__ __align__(16) short hb[64][104];           // GELU(H) chunk
    __shared__ float mean_s[64], rstd_s[64];

    const int tid  = threadIdx.x;
    const int wave = tid >> 6, lane = tid & 63;
    const int l16  = lane & 15, q8 = (lane >> 4) * 8, q4 = (lane >> 4) * 4;
    const int t0   = wave * 16;

    const short* w1_bf = wsw + WO_W1;
    const short* w2_bf = wsw + WO_W2;

    const int T0 = blockIdx.x * 64;
    const int b  = T0 / D_HW;
    const int p0 = T0 - b * D_HW;
    const int base = (b * 96) * D_HW + p0;

    // 1) attn tokens -> xs (coalesced global reads, chunk-swizzled LDS writes)
#pragma unroll
    for (int k = 0; k < 3; k++) {
        int idx = tid + k * 256;                     // < 768 = 64*12
        int t = idx / 12, s = idx - t * 12;
        *(short8*)&xs[t][(s ^ ((t >> 2) & 7)) << 3] =
            *(const short8*)&ytk[(T0 + t) * 96 + s * 8];
    }
    __syncthreads();                                 // [bar 1]

    // 2) compose y = x + attn: f32 in regs (24/thread), bf16 back into xs
    float yv[6][4];
#pragma unroll
    for (int k = 0; k < 6; k++) {
        int idx = tid + k * 256;                     // < 1536 = 96*16
        int c = idx >> 4, q = idx & 15;
        f32x4 xv = *(const f32x4*)&x[base + c * D_HW + q * 4];
        int ch = ((c >> 3) ^ (q & 7)) * 8 + (c & 7); // XCOL(q*4+j, c)
#pragma unroll
        for (int j = 0; j < 4; j++) {
            float v = xv[j] + s2f(xs[q * 4 + j][ch]);
            yv[k][j] = v;
            xs[q * 4 + j][ch] = f2s(v);
        }
    }
    __syncthreads();                                 // [bar 2]

    // 3) LN2 stats (4 lanes/token, own-wave rows)
    {
        int t = tid >> 2, p = tid & 3;
        float s = 0.f, s2 = 0.f;
#pragma unroll
        for (int i = 0; i < 6; i++) {
            int c = p * 24 + i * 4;
            s16x4 v4 = *(const s16x4*)&xs[t][XCOL(t, c)];
#pragma unroll
            for (int j = 0; j < 4; j++) { float v = s2f(v4[j]); s += v; s2 += v * v; }
        }
        s += __shfl_xor(s, 1); s2 += __shfl_xor(s2, 1);
        s += __shfl_xor(s, 2); s2 += __shfl_xor(s2, 2);
        if (p == 0) {
            float m = s * (1.f / 96.f);
            float var = s2 * (1.f / 96.f) - m * m;
            mean_s[t] = m; rstd_s[t] = rsqrtf(var + 1e-5f);
        }
    }

    // 4) hoist normalized A-frags (own rows, same-wave mean_s); xs dead after
    short8 xa[3];
    {
        int t = t0 + l16;
        float m = mean_s[t], rs = rstd_s[t];
        int key = (t >> 2) & 7;
#pragma unroll
        for (int kk = 0; kk < 3; kk++) {
            int ch = kk * 4 + (lane >> 4);
            xa[kk] = normfrag(&xs[t][(ch ^ key) << 3], n2g, n2b, ch * 8, m, rs);
        }
    }

    f32x4 c2[6];
#pragma unroll
    for (int nt = 0; nt < 6; nt++) c2[nt] = (f32x4){0.f, 0.f, 0.f, 0.f};

    // 5) 4 chunks; staging via register prefetch (issue early, write after bar)
    short8 pf[5];
#pragma unroll
    for (int k = 0; k < 5; k++) {
        int idx = tid + k * 256; if (idx > 1151) idx = 1151;
        pf[k] = *(const short8*)&w1_bf[idx * 8];
    }
#pragma unroll
    for (int jc = 0; jc < 4; jc++) {
        __syncthreads();   // jc=0: all xs reads done (wb aliases xs); jc>0: prev C2 wb reads done
        // write W1c
#pragma unroll
        for (int k = 0; k < 5; k++) {
            int idx = tid + k * 256;
            if (idx < 1152) { int j = idx / 12, s = idx - j * 12; *(short8*)&wb[j][s * 8] = pf[k]; }
        }
        __syncthreads();
        // issue W2c loads (consumed after next barrier)
#pragma unroll
        for (int k = 0; k < 5; k++) {
            int idx = tid + k * 256; if (idx > 1151) idx = 1151;
            int o = idx / 12, s = idx - o * 12;
            pf[k] = *(const short8*)&w2_bf[o * 384 + jc * 96 + s * 8];
        }
        // --- H = gelu(Xn W1c^T + b1) ---
#pragma unroll
        for (int nt = 0; nt < 6; nt++) {
            int jj = nt * 16 + l16;
            f32x4 acc = {0.f, 0.f, 0.f, 0.f};
            acc = MFMA(xa[0], *(const short8*)&wb[jj][q8],      acc);
            acc = MFMA(xa[1], *(const short8*)&wb[jj][32 + q8], acc);
            acc = MFMA(xa[2], *(const short8*)&wb[jj][64 + q8], acc);
            float bb = b1[jc * 96 + jj];
#pragma unroll
            for (int r = 0; r < 4; r++) {
                float v = acc[r] + bb;
                float g = 0.5f * v * (1.f + erf_fast(v * 0.7071067811865475f));
                hb[t0 + q4 + r][jj] = f2s(g);        // own rows
            }
        }
        __syncthreads();                             // all waves' W1c reads done
        // write W2c
#pragma unroll
        for (int k = 0; k < 5; k++) {
            int idx = tid + k * 256;
            if (idx < 1152) { int j = idx / 12, s = idx - j * 12; *(short8*)&wb[j][s * 8] = pf[k]; }
        }
        __syncthreads();
        // issue W1(jc+1) loads (consumed next iteration)
        if (jc < 3) {
#pragma unroll
            for (int k = 0; k < 5; k++) {
                int idx = tid + k * 256; if (idx > 1151) idx = 1151;
                pf[k] = *(const short8*)&w1_bf[(jc + 1) * 9216 + idx * 8];
            }
        }
        // --- C2 += H W2c^T (hb own rows) ---
        {
            short8 h0 = *(const short8*)&hb[t0 + l16][q8];
            short8 h1 = *(const short8*)&hb[t0 + l16][32 + q8];
            short8 h2 = *(const short8*)&hb[t0 + l16][64 + q8];
#pragma unroll
            for (int nt = 0; nt < 6; nt++) {
                int jj = nt * 16 + l16;
                c2[nt] = MFMA(h0, *(const short8*)&wb[jj][q8],      c2[nt]);
                c2[nt] = MFMA(h1, *(const short8*)&wb[jj][32 + q8], c2[nt]);
                c2[nt] = MFMA(h2, *(const short8*)&wb[jj][64 + q8], c2[nt]);
            }
        }
    }
    __syncthreads();       // [alias bar] last C2 wb reads done; xs may be written

    // 6) epilogue: mlp -> xs own rows (swizzled bf16), then out = yv + mlp
#pragma unroll
    for (int nt = 0; nt < 6; nt++) {
        int i = nt * 16 + l16;
        float bo = b2[i];
#pragma unroll
        for (int r = 0; r < 4; r++) {
            int t = t0 + q4 + r;
            xs[t][XCOL(t, i)] = f2s(bo + c2[nt][r]);
        }
    }
    __syncthreads();                                 // [bar 3]
#pragma unroll
    for (int k = 0; k < 6; k++) {
        int idx = tid + k * 256;
        int c = idx >> 4, q = idx & 15;
        int ch = ((c >> 3) ^ (q & 7)) * 8 + (c & 7);
        f32x4 o;
#pragma unroll
        for (int j = 0; j < 4; j++) o[j] = yv[k][j] + s2f(xs[q * 4 + j][ch]);
        *(f32x4*)&y[base + c * D_HW + q * 4] = o;
    }
}

// ===========================================================================
// FALLBACK PATH (used when ws_size < WS_NEED)
// ===========================================================================
__global__ __launch_bounds__(256, 3) void k_attn_f(
    const float* __restrict__ x, const float* __restrict__ n1g, const float* __restrict__ n1b,
    const float* __restrict__ qkvb, const float* __restrict__ relt,
    const float* __restrict__ projb, const short* __restrict__ wsw, float* __restrict__ y)
{
    __shared__ short qk[64][200];
    __shared__ short vt[96][72];
    __shared__ __align__(16) short xs[64][104];
    short (*ps)[72] = (short(*)[72])xs;
    __shared__ int   cnt_s[64];
    __shared__ float mean_s[64], rstd_s[64];

    const int tid  = threadIdx.x;
    const int wave = tid >> 6, lane = tid & 63;
    const int l16  = lane & 15, q8 = (lane >> 4) * 8, q4 = (lane >> 4) * 4;
    const int t0   = wave * 16;

    const short* qkvw_bf  = wsw + WO_QKVW;
    const short* projw_bf = wsw + WO_PROJW;

    const int wi = blockIdx.x;
    const int b  = wi >> 10, nw = wi & 1023;
    const int wh = nw >> 5, ww = nw & 31;
    const bool edge = (wh == 31) || (ww == 31);

    if (tid < 64) {
        int t = (tid < 49) ? tid : 48;
        int r = t / 7, c = t - r * 7;
        int sh = wh * 7 + r, sw = ww * 7 + c;
        int rh = (sh < 217) ? 0 : ((sh < 221) ? 1 : 2);
        int rw = (sw < 217) ? 0 : ((sw < 221) ? 1 : 2);
        cnt_s[tid] = rh * 3 + rw;
    }
    {
        int t = lane;
        int r = t / 7, cc = t - r * 7;
        int hh = wh * 7 + r + 3;  if (hh >= D_H) hh -= D_H;
        int w2 = ww * 7 + cc + 3; if (w2 >= D_W) w2 -= D_W;
        int off0 = (b * 96) * D_HW + hh * D_W + w2;
#pragma unroll
        for (int n = 0; n < 6; n++) {
            int c0 = wave * 24 + n * 4;
            s16x4 v4 = {0, 0, 0, 0};
            if (t < 49) {
                v4[0] = f2s(x[off0 + (c0 + 0) * D_HW]);
                v4[1] = f2s(x[off0 + (c0 + 1) * D_HW]);
                v4[2] = f2s(x[off0 + (c0 + 2) * D_HW]);
                v4[3] = f2s(x[off0 + (c0 + 3) * D_HW]);
            }
            *(s16x4*)&xs[t][c0] = v4;
        }
    }
    __syncthreads();
    {
        int t = tid >> 2, p = tid & 3;
        float s = 0.f, s2 = 0.f;
#pragma unroll
        for (int i = 0; i < 6; i++) {
            s16x4 v4 = *(const s16x4*)&xs[t][p * 24 + i * 4];
#pragma unroll
            for (int j = 0; j < 4; j++) { float v = s2f(v4[j]); s += v; s2 += v * v; }
        }
        s += __shfl_xor(s, 1); s2 += __shfl_xor(s2, 1);
        s += __shfl_xor(s, 2); s2 += __shfl_xor(s2, 2);
        if (p == 0) {
            float m = s * (1.f / 96.f);
            float var = s2 * (1.f / 96.f) - m * m;
            mean_s[t] = m; rstd_s[t] = rsqrtf(var + 1e-5f);
        }
    }
    __syncthreads();

    const float m0 = mean_s[t0 + l16], rs0 = rstd_s[t0 + l16];
    short8 a0 = normfrag(&xs[t0 + l16][q8],      n1g, n1b, q8,      m0, rs0);
    short8 a1 = normfrag(&xs[t0 + l16][32 + q8], n1g, n1b, 32 + q8, m0, rs0);
    short8 a2 = normfrag(&xs[t0 + l16][64 + q8], n1g, n1b, 64 + q8, m0, rs0);

#pragma unroll
    for (int jc = 0; jc < 3; jc++) {
#pragma unroll
        for (int nt = 0; nt < 6; nt++) {
            int jj = nt * 16 + l16;
            const short* wr = qkvw_bf + (jc * 96 + jj) * 96;
            f32x4 acc = {0.f, 0.f, 0.f, 0.f};
            acc = MFMA(a0, *(const short8*)&wr[q8],      acc);
            acc = MFMA(a1, *(const short8*)&wr[32 + q8], acc);
            acc = MFMA(a2, *(const short8*)&wr[64 + q8], acc);
            float bias = qkvb[jc * 96 + jj];
            if (jc == 0) {
#pragma unroll
                for (int r = 0; r < 4; r++) qk[t0 + q4 + r][jj] = f2s((acc[r] + bias) * SCALE);
            } else if (jc == 1) {
#pragma unroll
                for (int r = 0; r < 4; r++) qk[t0 + q4 + r][96 + jj] = f2s(acc[r] + bias);
            } else {
                s16x4 v4;
#pragma unroll
                for (int r = 0; r < 4; r++) v4[r] = f2s(acc[r] + bias);
                *(s16x4*)&vt[jj][t0 + q4] = v4;
            }
        }
    }

    float biasv[4][4][3];
#pragma unroll
    for (int nt = 0; nt < 4; nt++) {
        int m  = nt * 16 + l16;
        int mm = (m < 49) ? m : 48;
        int r2 = mm / 7, c2 = mm - r2 * 7;
        int cm = cnt_s[m];
#pragma unroll
        for (int r = 0; r < 4; r++) {
            int n  = t0 + q4 + r;
            int nn = (n < 49) ? n : 48;
            int r1 = nn / 7, c1 = nn - r1 * 7;
            int ri = ((r1 - r2 + 6) * 13 + (c1 - c2 + 6)) * 3;
            float mk = (edge && (cnt_s[n] != cm)) ? -100.f : 0.f;
            biasv[nt][r][0] = relt[ri + 0] + mk;
            biasv[nt][r][1] = relt[ri + 1] + mk;
            biasv[nt][r][2] = relt[ri + 2] + mk;
        }
    }
    const bool inval3 = (l16 != 0);

#pragma unroll
    for (int h = 0; h < 3; h++) {
        __syncthreads();
        short8 aq = *(const short8*)&qk[t0 + l16][h * 32 + q8];
        f32x4 sv[4];
#pragma unroll
        for (int nt = 0; nt < 4; nt++) {
            f32x4 z = {0.f, 0.f, 0.f, 0.f};
            sv[nt] = MFMA(aq, *(const short8*)&qk[nt * 16 + l16][96 + h * 32 + q8], z);
        }
        float mx[4] = {-1e30f, -1e30f, -1e30f, -1e30f};
#pragma unroll
        for (int nt = 0; nt < 4; nt++) {
#pragma unroll
            for (int r = 0; r < 4; r++) {
                float v = sv[nt][r] + biasv[nt][r][h];
                if (nt == 3 && inval3) v = -1e30f;
                sv[nt][r] = v;
                mx[r] = fmaxf(mx[r], v);
            }
        }
#pragma unroll
        for (int d = 1; d < 16; d <<= 1) {
#pragma unroll
            for (int r = 0; r < 4; r++) mx[r] = fmaxf(mx[r], __shfl_xor(mx[r], d));
        }
        float sm[4] = {0.f, 0.f, 0.f, 0.f};
#pragma unroll
        for (int nt = 0; nt < 4; nt++) {
#pragma unroll
            for (int r = 0; r < 4; r++) {
                float e = (nt == 3 && inval3) ? 0.f : __expf(sv[nt][r] - mx[r]);
                sv[nt][r] = e;
                sm[r] += e;
            }
        }
#pragma unroll
        for (int d = 1; d < 16; d <<= 1) {
#pragma unroll
            for (int r = 0; r < 4; r++) sm[r] += __shfl_xor(sm[r], d);
        }
        float inv[4];
#pragma unroll
        for (int r = 0; r < 4; r++) inv[r] = 1.f / sm[r];
#pragma unroll
        for (int nt = 0; nt < 4; nt++) {
#pragma unroll
            for (int r = 0; r < 4; r++)
                ps[t0 + q4 + r][nt * 16 + l16] = f2s(sv[nt][r] * inv[r]);
        }
        __syncthreads();
        short8 p0 = *(const short8*)&ps[t0 + l16][q8];
        short8 p1 = *(const short8*)&ps[t0 + l16][32 + q8];
#pragma unroll
        for (int nt = 0; nt < 2; nt++) {
            f32x4 acc = {0.f, 0.f, 0.f, 0.f};
            acc = MFMA(p0, *(const short8*)&vt[h * 32 + nt * 16 + l16][q8],      acc);
            acc = MFMA(p1, *(const short8*)&vt[h * 32 + nt * 16 + l16][32 + q8], acc);
            int d = nt * 16 + l16;
#pragma unroll
            for (int r = 0; r < 4; r++) {
                int t = t0 + q4 + r;
                if (t < 49) qk[t][h * 32 + d] = f2s(acc[r]);
            }
        }
    }

    __syncthreads();
    short8 o0 = *(const short8*)&qk[t0 + l16][q8];
    short8 o1 = *(const short8*)&qk[t0 + l16][32 + q8];
    short8 o2 = *(const short8*)&qk[t0 + l16][64 + q8];
    int  po[4];
    bool tv[4];
#pragma unroll
    for (int r = 0; r < 4; r++) {
        int t = t0 + q4 + r;
        tv[r] = (t < 49);
        int tt = tv[r] ? t : 0;
        int rr = tt / 7, cc = tt - rr * 7;
        int hh = wh * 7 + rr + 3;  if (hh >= D_H) hh -= D_H;
        int w2 = ww * 7 + cc + 3;  if (w2 >= D_W) w2 -= D_W;
        po[r] = (b * 96) * D_HW + hh * D_W + w2;
    }
#pragma unroll
    for (int nt = 0; nt < 6; nt++) {
        int i = nt * 16 + l16;
        const short* wr = projw_bf + i * 96;
        f32x4 acc = {0.f, 0.f, 0.f, 0.f};
        acc = MFMA(o0, *(const short8*)&wr[q8],      acc);
        acc = MFMA(o1, *(const short8*)&wr[32 + q8], acc);
        acc = MFMA(o2, *(const short8*)&wr[64 + q8], acc);
        float pb = projb[i];
#pragma unroll
        for (int r = 0; r < 4; r++) {
            if (tv[r]) {
                int off = po[r] + i * D_HW;
                y[off] = x[off] + acc[r] + pb;
            }
        }
    }
}

__global__ __launch_bounds__(256, 3) void k_mlp_f(
    float* __restrict__ y, const float* __restrict__ n2g, const float* __restrict__ n2b,
    const float* __restrict__ b1, const float* __restrict__ b2, const short* __restrict__ wsw)
{
    __shared__ short xs[128][104];
    __shared__ short hb[128][104];
    __shared__ float mean_s[128], rstd_s[128];

    const int tid  = threadIdx.x;
    const int wave = tid >> 6, lane = tid & 63;
    const int l16  = lane & 15, q8 = (lane >> 4) * 8, q4 = (lane >> 4) * 4;
    const int t0   = wave * 32;

    const short* w1_bf = wsw + WO_W1;
    const short* w2_bf = wsw + WO_W2;

    const int T0 = blockIdx.x * 128;
    const int b  = T0 / D_HW;
    const int p0 = T0 - b * D_HW;
    const int base = (b * 96) * D_HW + p0;

    for (int idx = tid; idx < 96 * 32; idx += 256) {
        int c = idx >> 5, q = idx & 31;
        f32x4 v4 = *(const f32x4*)&y[base + c * D_HW + q * 4];
        xs[q * 4 + 0][c] = f2s(v4[0]);
        xs[q * 4 + 1][c] = f2s(v4[1]);
        xs[q * 4 + 2][c] = f2s(v4[2]);
        xs[q * 4 + 3][c] = f2s(v4[3]);
    }
    __syncthreads();
    {
        int t = tid >> 1, p = tid & 1;
        float s = 0.f, s2 = 0.f;
#pragma unroll
        for (int i = 0; i < 12; i++) {
            s16x4 v4 = *(const s16x4*)&xs[t][p * 48 + i * 4];
#pragma unroll
            for (int j = 0; j < 4; j++) { float v = s2f(v4[j]); s += v; s2 += v * v; }
        }
        s += __shfl_xor(s, 1); s2 += __shfl_xor(s2, 1);
        float m = s * (1.f / 96.f);
        float var = s2 * (1.f / 96.f) - m * m;
        mean_s[t] = m; rstd_s[t] = rsqrtf(var + 1e-5f);
    }
    __syncthreads();

    short8 xa[2][3];
#pragma unroll
    for (int s = 0; s < 2; s++) {
        float m = mean_s[t0 + s * 16 + l16], rs = rstd_s[t0 + s * 16 + l16];
#pragma unroll
        for (int kk = 0; kk < 3; kk++)
            xa[s][kk] = normfrag(&xs[t0 + s * 16 + l16][kk * 32 + q8], n2g, n2b,
                                 kk * 32 + q8, m, rs);
    }

    f32x4 c2[2][6];
#pragma unroll
    for (int s = 0; s < 2; s++)
#pragma unroll
        for (int nt = 0; nt < 6; nt++) c2[s][nt] = (f32x4){0.f, 0.f, 0.f, 0.f};

    for (int jc = 0; jc < 4; jc++) {
#pragma unroll
        for (int s = 0; s < 2; s++) {
#pragma unroll
            for (int nt = 0; nt < 6; nt++) {
                int jj = nt * 16 + l16;
                const short* wr = w1_bf + (jc * 96 + jj) * 96;
                f32x4 acc = {0.f, 0.f, 0.f, 0.f};
                acc = MFMA(xa[s][0], *(const short8*)&wr[q8],      acc);
                acc = MFMA(xa[s][1], *(const short8*)&wr[32 + q8], acc);
                acc = MFMA(xa[s][2], *(const short8*)&wr[64 + q8], acc);
                float bb = b1[jc * 96 + jj];
#pragma unroll
                for (int r = 0; r < 4; r++) {
                    float v = acc[r] + bb;
                    float g = 0.5f * v * (1.f + erf_fast(v * 0.7071067811865475f));
                    hb[t0 + s * 16 + q4 + r][jj] = f2s(g);
                }
            }
        }
        __syncthreads();
#pragma unroll
        for (int s = 0; s < 2; s++) {
            short8 h0 = *(const short8*)&hb[t0 + s * 16 + l16][q8];
            short8 h1 = *(const short8*)&hb[t0 + s * 16 + l16][32 + q8];
            short8 h2 = *(const short8*)&hb[t0 + s * 16 + l16][64 + q8];
#pragma unroll
            for (int nt = 0; nt < 6; nt++) {
                const short* wr = w2_bf + (nt * 16 + l16) * 384 + jc * 96;
                c2[s][nt] = MFMA(h0, *(const short8*)&wr[q8],      c2[s][nt]);
                c2[s][nt] = MFMA(h1, *(const short8*)&wr[32 + q8], c2[s][nt]);
                c2[s][nt] = MFMA(h2, *(const short8*)&wr[64 + q8], c2[s][nt]);
            }
        }
        __syncthreads();
    }

#pragma unroll
    for (int s = 0; s < 2; s++)
#pragma unroll
        for (int nt = 0; nt < 6; nt++) {
            int i = nt * 16 + l16;
            float bo = b2[i];
#pragma unroll
            for (int r = 0; r < 4; r++)
                xs[t0 + s * 16 + q4 + r][i] = f2s(bo + c2[s][nt][r]);
        }
    __syncthreads();
    for (int idx = tid; idx < 96 * 32; idx += 256) {
        int c = idx >> 5, q = idx & 31;
        int off = base + c * D_HW + q * 4;
        f32x4 v4 = *(const f32x4*)&y[off];
        v4[0] += s2f(xs[q * 4 + 0][c]);
        v4[1] += s2f(xs[q * 4 + 1][c]);
        v4[2] += s2f(xs[q * 4 + 2][c]);
        v4[3] += s2f(xs[q * 4 + 3][c]);
        *(f32x4*)&y[off] = v4;
    }
}

extern "C" void kernel_launch(void* const* d_in, const int* in_sizes, int n_in,
                              void* d_out, int out_size, void* d_ws, size_t ws_size,
                              hipStream_t stream) {
    const float* x    = (const float*)d_in[0];
    const float* n1g  = (const float*)d_in[1];
    const float* n1b  = (const float*)d_in[2];
    const float* qkvw = (const float*)d_in[3];
    const float* qkvb = (const float*)d_in[4];
    const float* relt = (const float*)d_in[5];
    const float* projw= (const float*)d_in[6];
    const float* projb= (const float*)d_in[7];
    const float* n2g  = (const float*)d_in[8];
    const float* n2b  = (const float*)d_in[9];
    const float* w1   = (const float*)d_in[10];
    const float* b1   = (const float*)d_in[11];
    const float* w2   = (const float*)d_in[12];
    const float* b2   = (const float*)d_in[13];
    float* y  = (float*)d_out;
    short* ws = (short*)d_ws;

    if (ws_size >= WS_NEED) {
        short* xt  = ws + XT_SH;
        short* ytk = ws + YT_SH;
        short* wbf = ws + W_SH;
        k_prep<<<108, 256, 0, stream>>>(qkvw, projw, w1, w2, wbf);
        k_t<<<1792, 256, 0, stream>>>(x, n1g, n1b, xt);
        k_attn_t<<<8192, 256, 0, stream>>>(xt, qkvb, relt, projb, wbf, ytk);
        k_mlp_t<<<6272, 256, 0, stream>>>(x, ytk, y, n2g, n2b, b1, b2, wbf);
    } else {
        k_prep<<<108, 256, 0, stream>>>(qkvw, projw, w1, w2, ws);
        k_attn_f<<<8192, 256, 0, stream>>>(x, n1g, n1b, qkvb, relt, projb, ws, y);
        k_mlp_f<<<3136, 256, 0, stream>>>(y, n2g, n2b, b1, b2, ws);
    }
}

// Round 11
// 619.576 us; speedup vs baseline: 1.0926x; 1.0200x over previous
//
#include <hip/hip_runtime.h>
#include <hip/hip_bf16.h>

typedef __attribute__((ext_vector_type(8))) short short8;
typedef __attribute__((ext_vector_type(4))) short s16x4;
typedef __attribute__((ext_vector_type(4))) float f32x4;

#define D_H   224
#define D_W   224
#define D_HW  50176
#define SCALE 0.17677669529663687f  // 32^-0.5

// weight sub-offsets (shorts, relative to weight base)
#define WO_QKVW  0        // 27648
#define WO_PROJW 27648    // 9216
#define WO_W1    36864    // 36864
#define WO_W2    73728    // 36864
#define WO_TOT   110592

// big-workspace layout (shorts)
#define XT_SH 0                       // 8*224*224*96 = 38535168 bf16 (LN1-normalized)
#define YT_SH 38535168                // same size
#define W_SH  77070336                // weights
#define WS_NEED ((size_t)(77070336 + 110592) * 2)   // 154,361,856 B

static __device__ __forceinline__ short f2s(float v) {
    union { __hip_bfloat16 b; short s; } u; u.b = __float2bfloat16(v); return u.s;
}
static __device__ __forceinline__ float s2f(short s) {
    union { short s; __hip_bfloat16 b; } u; u.s = s; return __bfloat162float(u.b);
}

#define MFMA(a, b, c) __builtin_amdgcn_mfma_f32_16x16x32_bf16((a), (b), (c), 0, 0, 0)

static __device__ __forceinline__ short8 normfrag(const short* p, const float* g,
                                                  const float* b, int c0, float m, float rs) {
    short8 r = *(const short8*)p;
    short8 o;
#pragma unroll
    for (int j = 0; j < 8; j++) o[j] = f2s((s2f(r[j]) - m) * rs * g[c0 + j] + b[c0 + j]);
    return o;
}

// A&S 7.1.26 erf approximation (fallback path gelu)
static __device__ __forceinline__ float erf_fast(float x) {
    float a = fabsf(x);
    float t = __builtin_amdgcn_rcpf(1.f + 0.3275911f * a);
    float p = t * (0.254829592f + t * (-0.284496736f + t * (1.421413741f +
              t * (-1.453152027f + t * 1.061405429f))));
    float y = 1.f - p * __expf(-a * a);
    return copysignf(y, x);
}

// tanh-form GELU: 0.5x(1+tanh(0.79788(x+0.044715x^3))); max err ~3e-4 vs erf
// (invisible under bf16 storage). ~11 VALU ops vs ~19 for erf_fast wrapper.
static __device__ __forceinline__ float gelu_fast(float x) {
    float u = x * x;
    float t = x * (0.7978845608f + 0.0356774081f * u);
    float e = __expf(2.f * t);
    float th = 1.f - 2.f * __builtin_amdgcn_rcpf(1.f + e);
    return 0.5f * x * (1.f + th);
}

// ---------------------------------------------------------------------------
// K0: one-shot f32 -> bf16 weight conversion (fallback path only; main path
// does this in k_t tail blocks)
// ---------------------------------------------------------------------------
__global__ __launch_bounds__(256) void k_prep(
    const float* __restrict__ qkvw, const float* __restrict__ projw,
    const float* __restrict__ w1, const float* __restrict__ w2, short* __restrict__ ws)
{
    int i4 = blockIdx.x * 256 + threadIdx.x;         // 27648 f32x4 groups total
    const float* src; int off;
    if (i4 < 6912)        { src = qkvw;  off = 0; }
    else if (i4 < 9216)   { src = projw; off = 6912; }
    else if (i4 < 18432)  { src = w1;    off = 9216; }
    else                  { src = w2;    off = 18432; }
    f32x4 v = *(const f32x4*)&src[(i4 - off) * 4];
    s16x4 s;
#pragma unroll
    for (int j = 0; j < 4; j++) s[j] = f2s(v[j]);
    *(s16x4*)&ws[i4 * 4] = s;
}

// ---------------------------------------------------------------------------
// KT (v5): blocks 0..1791: x (B,C,H,W) f32 -> xt (B,H,W,C) bf16, LN1 FUSED.
//          blocks 1792..1899: weight f32 -> bf16 prep (merged launch).
// ---------------------------------------------------------------------------
__global__ __launch_bounds__(256) void k_t(
    const float* __restrict__ x, const float* __restrict__ n1g,
    const float* __restrict__ n1b, short* __restrict__ xt,
    const float* __restrict__ qkvw, const float* __restrict__ projw,
    const float* __restrict__ w1, const float* __restrict__ w2, short* __restrict__ wsw)
{
    const int bh = blockIdx.x;
    if (bh >= 1792) {                    // weight prep tail
        int i4 = (bh - 1792) * 256 + threadIdx.x;    // < 27648
        const float* src; int off;
        if (i4 < 6912)        { src = qkvw;  off = 0; }
        else if (i4 < 9216)   { src = projw; off = 6912; }
        else if (i4 < 18432)  { src = w1;    off = 9216; }
        else                  { src = w2;    off = 18432; }
        f32x4 v = *(const f32x4*)&src[(i4 - off) * 4];
        s16x4 s;
#pragma unroll
        for (int j = 0; j < 4; j++) s[j] = f2s(v[j]);
        *(s16x4*)&wsw[i4 * 4] = s;
        return;
    }

    __shared__ short tile[224][128];     // 57344 B; 32 slots x 4 shorts per row
    __shared__ float mean_s[224], rstd_s[224];
    const int tid = threadIdx.x;
    const int b = bh / 224, h = bh - b * 224;
    const int pbase = (b * 96) * D_HW + h * 224;

#pragma unroll
    for (int k = 0; k < 6; k++) {
        int idx = tid + k * 256;         // valid < 1344 = 24 c-quads * 56 w-quads
        if (idx < 1344) {
            int c4 = idx / 56, w4 = idx - c4 * 56;
            float vv[4][4];
#pragma unroll
            for (int j = 0; j < 4; j++) {
                f32x4 v = *(const f32x4*)&x[pbase + (c4 * 4 + j) * D_HW + w4 * 4];
#pragma unroll
                for (int i = 0; i < 4; i++) vv[j][i] = v[i];
            }
#pragma unroll
            for (int i = 0; i < 4; i++) {
                int w = w4 * 4 + i;
                s16x4 o;
#pragma unroll
                for (int j = 0; j < 4; j++) o[j] = f2s(vv[j][i]);
                *(s16x4*)&tile[w][(c4 ^ (w & 31)) * 4] = o;
            }
        }
    }
    __syncthreads();
    // ---- LN1 stats: one thread per token ----
    if (tid < 224) {
        int key = tid & 31;
        float s = 0.f, s2 = 0.f;
#pragma unroll
        for (int c4 = 0; c4 < 24; c4++) {
            s16x4 v4 = *(const s16x4*)&tile[tid][(c4 ^ key) << 2];
#pragma unroll
            for (int j = 0; j < 4; j++) { float v = s2f(v4[j]); s += v; s2 += v * v; }
        }
        float m = s * (1.f / 96.f);
        float var = s2 * (1.f / 96.f) - m * m;
        mean_s[tid] = m; rstd_s[tid] = rsqrtf(var + 1e-5f);
    }
    __syncthreads();
    // ---- normalize + coalesced streamout ----
    const int obase = ((b * 224 + h) * 224) * 96;
#pragma unroll
    for (int k = 0; k < 11; k++) {
        int idx = tid + k * 256;         // valid < 2688 = 224*12
        if (idx < 2688) {
            int w = idx / 12, s = idx - w * 12;
            int kk = w & 31;
            s16x4 a = *(const s16x4*)&tile[w][((2 * s) ^ kk) << 2];
            s16x4 c = *(const s16x4*)&tile[w][((2 * s + 1) ^ kk) << 2];
            float m = mean_s[w], rs = rstd_s[w];
            f32x4 g0 = *(const f32x4*)&n1g[s * 8];
            f32x4 g1 = *(const f32x4*)&n1g[s * 8 + 4];
            f32x4 b0 = *(const f32x4*)&n1b[s * 8];
            f32x4 b1 = *(const f32x4*)&n1b[s * 8 + 4];
            short8 o;
#pragma unroll
            for (int j = 0; j < 4; j++) o[j]     = f2s((s2f(a[j]) - m) * rs * g0[j] + b0[j]);
#pragma unroll
            for (int j = 0; j < 4; j++) o[4 + j] = f2s((s2f(c[j]) - m) * rs * g1[j] + b1[j]);
            *(short8*)&xt[obase + w * 96 + s * 8] = o;
        }
    }
}

// ---------------------------------------------------------------------------
// K1 (v9): one block per window, token-major NORMALIZED bf16 in, bf16 out.
//   4 barriers; 2-deep register prefetch of direct-global W frags;
//   deferred softmax normalization (inv folded into PV epilogue).
// ---------------------------------------------------------------------------
__global__ __launch_bounds__(256, 3) void k_attn_t(
    const short* __restrict__ xt, const float* __restrict__ qkvb,
    const float* __restrict__ relt, const float* __restrict__ projb,
    const short* __restrict__ wsw, short* __restrict__ yt)
{
    __shared__ short qk[64][200];                    // Q(0..95 pre-scaled) K(96..191); PV/proj out
    __shared__ __align__(16) short region[11520];    // [ps 4608][vt 6912] shorts
    short (*xs)[104] = (short(*)[104])region;        // normalized tokens, pre-QKV only
    short (*ps)[72]  = (short(*)[72])region;         // P matrix (heads phase)
    short (*vt)[72]  = (short(*)[72])(region + 4608);// V d-major (96 rows x 72)
    __shared__ int   cnt_s[64];

    const int tid  = threadIdx.x;
    const int wave = tid >> 6, lane = tid & 63;
    const int l16  = lane & 15, q8 = (lane >> 4) * 8, q4 = (lane >> 4) * 4;
    const int t0   = wave * 16;

    const short* qkvw_bf  = wsw + WO_QKVW;
    const short* projw_bf = wsw + WO_PROJW;

    const int wi = blockIdx.x;
    const int b  = wi >> 10, nw = wi & 1023;
    const int wh = nw >> 5, ww = nw & 31;
    const bool edge = (wh == 31) || (ww == 31);

    if (tid < 64) {
        int t = (tid < 49) ? tid : 48;
        int r = t / 7, c = t - r * 7;
        int sh = wh * 7 + r, sw = ww * 7 + c;
        int rh = (sh < 217) ? 0 : ((sh < 221) ? 1 : 2);
        int rw = (sw < 217) ? 0 : ((sw < 221) ? 1 : 2);
        cnt_s[tid] = rh * 3 + rw;
    }
    // ---- gather: 64 tokens x 12 16B-segments from xt (already normalized) ----
#pragma unroll
    for (int k = 0; k < 3; k++) {
        int idx = tid + k * 256;                     // < 768 = 64*12
        int t = idx / 12, s = idx - t * 12;
        short8 v = {0, 0, 0, 0, 0, 0, 0, 0};
        if (t < 49) {
            int r = t / 7, cc = t - r * 7;
            int hh = wh * 7 + r + 3;  if (hh >= D_H) hh -= D_H;
            int w2 = ww * 7 + cc + 3; if (w2 >= D_W) w2 -= D_W;
            v = *(const short8*)&xt[((b * 224 + hh) * 224 + w2) * 96 + s * 8];
        }
        *(short8*)&xs[t][s * 8] = v;
    }
    __syncthreads();                                 // [bar 1] xs + cnt_s visible

    // ---- A-frags: plain vector loads (normalization already applied) ----
    short8 a0 = *(const short8*)&xs[t0 + l16][q8];
    short8 a1 = *(const short8*)&xs[t0 + l16][32 + q8];
    short8 a2 = *(const short8*)&xs[t0 + l16][64 + q8];

    // issue first QKV W-group loads early (hide under barrier drain)
    short8 wA0, wA1, wA2, wB0, wB1, wB2;
    {
        const short* w = qkvw_bf + l16 * 96;         // g=0: jc=0, nt=0
        wA0 = *(const short8*)&w[q8];
        wA1 = *(const short8*)&w[32 + q8];
        wA2 = *(const short8*)&w[64 + q8];
    }
    __syncthreads();                                 // [bar 2] all xs reads done (vt overwrites)

    // ---- QKV: 18 groups, 2-deep register-pipelined W loads ----
#pragma unroll
    for (int g = 0; g < 18; g++) {
        const int jc = g / 6, nt = g - jc * 6;
        const int jj = nt * 16 + l16;
        if (g < 17) {
            int g2 = g + 1, jc2 = g2 / 6, nt2 = g2 - jc2 * 6;
            const short* w = qkvw_bf + (jc2 * 96 + nt2 * 16 + l16) * 96;
            wB0 = *(const short8*)&w[q8];
            wB1 = *(const short8*)&w[32 + q8];
            wB2 = *(const short8*)&w[64 + q8];
        }
        f32x4 acc = {0.f, 0.f, 0.f, 0.f};
        acc = MFMA(a0, wA0, acc);
        acc = MFMA(a1, wA1, acc);
        acc = MFMA(a2, wA2, acc);
        float bias = qkvb[jc * 96 + jj];
        if (jc == 0) {
#pragma unroll
            for (int r = 0; r < 4; r++) qk[t0 + q4 + r][jj] = f2s((acc[r] + bias) * SCALE);
        } else if (jc == 1) {
#pragma unroll
            for (int r = 0; r < 4; r++) qk[t0 + q4 + r][96 + jj] = f2s(acc[r] + bias);
        } else {
            s16x4 v4;
#pragma unroll
            for (int r = 0; r < 4; r++) v4[r] = f2s(acc[r] + bias);
            *(s16x4*)&vt[jj][t0 + q4] = v4;
        }
        wA0 = wB0; wA1 = wB1; wA2 = wB2;
    }

    // ---- per-lane rel-pos bias + mask in registers (VALU, overlaps pipeline) ----
    float biasv[4][4][3];
#pragma unroll
    for (int nt = 0; nt < 4; nt++) {
        int m  = nt * 16 + l16;
        int mm = (m < 49) ? m : 48;
        int r2 = mm / 7, c2 = mm - r2 * 7;
        int cm = cnt_s[m];
#pragma unroll
        for (int r = 0; r < 4; r++) {
            int n  = t0 + q4 + r;
            int nn = (n < 49) ? n : 48;
            int r1 = nn / 7, c1 = nn - r1 * 7;
            int ri = ((r1 - r2 + 6) * 13 + (c1 - c2 + 6)) * 3;
            float mk = (edge && (cnt_s[n] != cm)) ? -100.f : 0.f;
            biasv[nt][r][0] = relt[ri + 0] + mk;
            biasv[nt][r][1] = relt[ri + 1] + mk;
            biasv[nt][r][2] = relt[ri + 2] + mk;
        }
    }
    const bool inval3 = (l16 != 0);

    __syncthreads();                                 // [bar 3] K + V visible to all waves

    // ---- attention heads: zero internal barriers ----
#pragma unroll
    for (int h = 0; h < 3; h++) {
        short8 aq = *(const short8*)&qk[t0 + l16][h * 32 + q8];  // own rows
        f32x4 sv[4];
#pragma unroll
        for (int nt = 0; nt < 4; nt++) {
            f32x4 z = {0.f, 0.f, 0.f, 0.f};
            sv[nt] = MFMA(aq, *(const short8*)&qk[nt * 16 + l16][96 + h * 32 + q8], z);
        }
        float mx[4] = {-1e30f, -1e30f, -1e30f, -1e30f};
#pragma unroll
        for (int nt = 0; nt < 4; nt++) {
#pragma unroll
            for (int r = 0; r < 4; r++) {
                float v = sv[nt][r] + biasv[nt][r][h];
                if (nt == 3 && inval3) v = -1e30f;
                sv[nt][r] = v;
                mx[r] = fmaxf(mx[r], v);
            }
        }
#pragma unroll
        for (int d = 1; d < 16; d <<= 1) {
#pragma unroll
            for (int r = 0; r < 4; r++) mx[r] = fmaxf(mx[r], __shfl_xor(mx[r], d));
        }
        float sm[4] = {0.f, 0.f, 0.f, 0.f};
#pragma unroll
        for (int nt = 0; nt < 4; nt++) {
#pragma unroll
            for (int r = 0; r < 4; r++) {
                float e = (nt == 3 && inval3) ? 0.f : __expf(sv[nt][r] - mx[r]);
                sv[nt][r] = e;
                sm[r] += e;
            }
        }
#pragma unroll
        for (int d = 1; d < 16; d <<= 1) {
#pragma unroll
            for (int r = 0; r < 4; r++) sm[r] += __shfl_xor(sm[r], d);
        }
        float inv[4];
#pragma unroll
        for (int r = 0; r < 4; r++) inv[r] = __builtin_amdgcn_rcpf(sm[r]);
        // deferred normalization: store raw e (<=1); inv applied in PV epilogue
#pragma unroll
        for (int nt = 0; nt < 4; nt++) {
#pragma unroll
            for (int r = 0; r < 4; r++)
                ps[t0 + q4 + r][nt * 16 + l16] = f2s(sv[nt][r]);           // own rows
        }
        short8 p0 = *(const short8*)&ps[t0 + l16][q8];
        short8 p1 = *(const short8*)&ps[t0 + l16][32 + q8];
#pragma unroll
        for (int nt = 0; nt < 2; nt++) {
            f32x4 acc = {0.f, 0.f, 0.f, 0.f};
            acc = MFMA(p0, *(const short8*)&vt[h * 32 + nt * 16 + l16][q8],      acc);
            acc = MFMA(p1, *(const short8*)&vt[h * 32 + nt * 16 + l16][32 + q8], acc);
            int d = nt * 16 + l16;
#pragma unroll
            for (int r = 0; r < 4; r++) {
                int t = t0 + q4 + r;
                if (t < 49) qk[t][h * 32 + d] = f2s(acc[r] * inv[r]);       // own rows
            }
        }
    }

    // ---- proj: 6 groups, 2-deep register-pipelined W loads ----
    {
        const short* w = projw_bf + l16 * 96;        // g=0
        wA0 = *(const short8*)&w[q8];
        wA1 = *(const short8*)&w[32 + q8];
        wA2 = *(const short8*)&w[64 + q8];
    }
    short8 o0 = *(const short8*)&qk[t0 + l16][q8];
    short8 o1 = *(const short8*)&qk[t0 + l16][32 + q8];
    short8 o2 = *(const short8*)&qk[t0 + l16][64 + q8];
#pragma unroll
    for (int nt = 0; nt < 6; nt++) {
        int i = nt * 16 + l16;
        if (nt < 5) {
            const short* w = projw_bf + ((nt + 1) * 16 + l16) * 96;
            wB0 = *(const short8*)&w[q8];
            wB1 = *(const short8*)&w[32 + q8];
            wB2 = *(const short8*)&w[64 + q8];
        }
        f32x4 acc = {0.f, 0.f, 0.f, 0.f};
        acc = MFMA(o0, wA0, acc);
        acc = MFMA(o1, wA1, acc);
        acc = MFMA(o2, wA2, acc);
        float pb = projb[i];
#pragma unroll
        for (int r = 0; r < 4; r++) {
            int t = t0 + q4 + r;
            if (t < 49) qk[t][i] = f2s(acc[r] + pb);
        }
        wA0 = wB0; wA1 = wB1; wA2 = wB2;
    }
    __syncthreads();                                 // [bar 4] proj out visible
#pragma unroll
    for (int k = 0; k < 3; k++) {
        int idx = tid + k * 256;
        if (idx < 588) {                             // 49*12
            int t = idx / 12, s = idx - t * 12;
            int r = t / 7, cc = t - r * 7;
            int hh = wh * 7 + r + 3;  if (hh >= D_H) hh -= D_H;
            int w2 = ww * 7 + cc + 3; if (w2 >= D_W) w2 -= D_W;
            *(short8*)&yt[((b * 224 + hh) * 224 + w2) * 96 + s * 8] =
                *(const short8*)&qk[t][s * 8];
        }
    }
}

// ---------------------------------------------------------------------------
// K2 (v9): MLP, 64 tokens/block. Staged-wb with wb ALIASED over dead xs:
//   LDS 33.8 KB. Register-prefetch staging. tanh-form fast GELU.
// ---------------------------------------------------------------------------
#define XCOL(row, c) ((((((c) >> 3) ^ (((row) >> 2) & 7)) << 3)) | ((c) & 7))

__global__ __launch_bounds__(256, 3) void k_mlp_t(
    const float* __restrict__ x, const short* __restrict__ ytk, float* __restrict__ y,
    const float* __restrict__ n2g, const float* __restrict__ n2b,
    const float* __restrict__ b1, const float* __restrict__ b2, const short* __restrict__ wsw)
{
    __shared__ __align__(16) char region[96 * 104 * 2];   // 19968 B: xs then wb
    short (*xs)[128] = (short(*)[128])region;             // 64*128*2 = 16384 <= 19968
    short (*wb)[104] = (short(*)[104])region;             // staged W chunk (96 rows)
    __shared__ __align__(16) short hb[64][104];           // GELU(H) chunk
    __shared__ float mean_s[64], rstd_s[64];

    const int tid  = threadIdx.x;
    const int wave = tid >> 6, lane = tid & 63;
    const int l16  = lane & 15, q8 = (lane >> 4) * 8, q4 = (lane >> 4) * 4;
    const int t0   = wave * 16;

    const short* w1_bf = wsw + WO_W1;
    const short* w2_bf = wsw + WO_W2;

    const int T0 = blockIdx.x * 64;
    const int b  = T0 / D_HW;
    const int p0 = T0 - b * D_HW;
    const int base = (b * 96) * D_HW + p0;

    // 1) attn tokens -> xs (coalesced global reads, chunk-swizzled LDS writes)
#pragma unroll
    for (int k = 0; k < 3; k++) {
        int idx = tid + k * 256;                     // < 768 = 64*12
        int t = idx / 12, s = idx - t * 12;
        *(short8*)&xs[t][(s ^ ((t >> 2) & 7)) << 3] =
            *(const short8*)&ytk[(T0 + t) * 96 + s * 8];
    }
    __syncthreads();                                 // [bar 1]

    // 2) compose y = x + attn: f32 in regs (24/thread), bf16 back into xs
    float yv[6][4];
#pragma unroll
    for (int k = 0; k < 6; k++) {
        int idx = tid + k * 256;                     // < 1536 = 96*16
        int c = idx >> 4, q = idx & 15;
        f32x4 xv = *(const f32x4*)&x[base + c * D_HW + q * 4];
        int ch = ((c >> 3) ^ (q & 7)) * 8 + (c & 7); // XCOL(q*4+j, c)
#pragma unroll
        for (int j = 0; j < 4; j++) {
            float v = xv[j] + s2f(xs[q * 4 + j][ch]);
            yv[k][j] = v;
            xs[q * 4 + j][ch] = f2s(v);
        }
    }
    __syncthreads();                                 // [bar 2]

    // 3) LN2 stats (4 lanes/token, own-wave rows)
    {
        int t = tid >> 2, p = tid & 3;
        float s = 0.f, s2 = 0.f;
#pragma unroll
        for (int i = 0; i < 6; i++) {
            int c = p * 24 + i * 4;
            s16x4 v4 = *(const s16x4*)&xs[t][XCOL(t, c)];
#pragma unroll
            for (int j = 0; j < 4; j++) { float v = s2f(v4[j]); s += v; s2 += v * v; }
        }
        s += __shfl_xor(s, 1); s2 += __shfl_xor(s2, 1);
        s += __shfl_xor(s, 2); s2 += __shfl_xor(s2, 2);
        if (p == 0) {
            float m = s * (1.f / 96.f);
            float var = s2 * (1.f / 96.f) - m * m;
            mean_s[t] = m; rstd_s[t] = rsqrtf(var + 1e-5f);
        }
    }

    // 4) hoist normalized A-frags (own rows, same-wave mean_s); xs dead after
    short8 xa[3];
    {
        int t = t0 + l16;
        float m = mean_s[t], rs = rstd_s[t];
        int key = (t >> 2) & 7;
#pragma unroll
        for (int kk = 0; kk < 3; kk++) {
            int ch = kk * 4 + (lane >> 4);
            xa[kk] = normfrag(&xs[t][(ch ^ key) << 3], n2g, n2b, ch * 8, m, rs);
        }
    }

    f32x4 c2[6];
#pragma unroll
    for (int nt = 0; nt < 6; nt++) c2[nt] = (f32x4){0.f, 0.f, 0.f, 0.f};

    // 5) 4 chunks; staging via register prefetch (issue early, write after bar)
    short8 pf[5];
#pragma unroll
    for (int k = 0; k < 5; k++) {
        int idx = tid + k * 256; if (idx > 1151) idx = 1151;
        pf[k] = *(const short8*)&w1_bf[idx * 8];
    }
#pragma unroll
    for (int jc = 0; jc < 4; jc++) {
        __syncthreads();   // jc=0: all xs reads done (wb aliases xs); jc>0: prev C2 wb reads done
        // write W1c
#pragma unroll
        for (int k = 0; k < 5; k++) {
            int idx = tid + k * 256;
            if (idx < 1152) { int j = idx / 12, s = idx - j * 12; *(short8*)&wb[j][s * 8] = pf[k]; }
        }
        __syncthreads();
        // issue W2c loads (consumed after next barrier)
#pragma unroll
        for (int k = 0; k < 5; k++) {
            int idx = tid + k * 256; if (idx > 1151) idx = 1151;
            int o = idx / 12, s = idx - o * 12;
            pf[k] = *(const short8*)&w2_bf[o * 384 + jc * 96 + s * 8];
        }
        // --- H = gelu(Xn W1c^T + b1) ---
#pragma unroll
        for (int nt = 0; nt < 6; nt++) {
            int jj = nt * 16 + l16;
            f32x4 acc = {0.f, 0.f, 0.f, 0.f};
            acc = MFMA(xa[0], *(const short8*)&wb[jj][q8],      acc);
            acc = MFMA(xa[1], *(const short8*)&wb[jj][32 + q8], acc);
            acc = MFMA(xa[2], *(const short8*)&wb[jj][64 + q8], acc);
            float bb = b1[jc * 96 + jj];
#pragma unroll
            for (int r = 0; r < 4; r++) {
                float v = acc[r] + bb;
                hb[t0 + q4 + r][jj] = f2s(gelu_fast(v));   // own rows
            }
        }
        __syncthreads();                             // all waves' W1c reads done
        // write W2c
#pragma unroll
        for (int k = 0; k < 5; k++) {
            int idx = tid + k * 256;
            if (idx < 1152) { int j = idx / 12, s = idx - j * 12; *(short8*)&wb[j][s * 8] = pf[k]; }
        }
        __syncthreads();
        // issue W1(jc+1) loads (consumed next iteration)
        if (jc < 3) {
#pragma unroll
            for (int k = 0; k < 5; k++) {
                int idx = tid + k * 256; if (idx > 1151) idx = 1151;
                pf[k] = *(const short8*)&w1_bf[(jc + 1) * 9216 + idx * 8];
            }
        }
        // --- C2 += H W2c^T (hb own rows) ---
        {
            short8 h0 = *(const short8*)&hb[t0 + l16][q8];
            short8 h1 = *(const short8*)&hb[t0 + l16][32 + q8];
            short8 h2 = *(const short8*)&hb[t0 + l16][64 + q8];
#pragma unroll
            for (int nt = 0; nt < 6; nt++) {
                int jj = nt * 16 + l16;
                c2[nt] = MFMA(h0, *(const short8*)&wb[jj][q8],      c2[nt]);
                c2[nt] = MFMA(h1, *(const short8*)&wb[jj][32 + q8], c2[nt]);
                c2[nt] = MFMA(h2, *(const short8*)&wb[jj][64 + q8], c2[nt]);
            }
        }
    }
    __syncthreads();       // [alias bar] last C2 wb reads done; xs may be written

    // 6) epilogue: mlp -> xs own rows (swizzled bf16), then out = yv + mlp
#pragma unroll
    for (int nt = 0; nt < 6; nt++) {
        int i = nt * 16 + l16;
        float bo = b2[i];
#pragma unroll
        for (int r = 0; r < 4; r++) {
            int t = t0 + q4 + r;
            xs[t][XCOL(t, i)] = f2s(bo + c2[nt][r]);
        }
    }
    __syncthreads();                                 // [bar 3]
#pragma unroll
    for (int k = 0; k < 6; k++) {
        int idx = tid + k * 256;
        int c = idx >> 4, q = idx & 15;
        int ch = ((c >> 3) ^ (q & 7)) * 8 + (c & 7);
        f32x4 o;
#pragma unroll
        for (int j = 0; j < 4; j++) o[j] = yv[k][j] + s2f(xs[q * 4 + j][ch]);
        *(f32x4*)&y[base + c * D_HW + q * 4] = o;
    }
}

// ===========================================================================
// FALLBACK PATH (used when ws_size < WS_NEED)
// ===========================================================================
__global__ __launch_bounds__(256, 3) void k_attn_f(
    const float* __restrict__ x, const float* __restrict__ n1g, const float* __restrict__ n1b,
    const float* __restrict__ qkvb, const float* __restrict__ relt,
    const float* __restrict__ projb, const short* __restrict__ wsw, float* __restrict__ y)
{
    __shared__ short qk[64][200];
    __shared__ short vt[96][72];
    __shared__ __align__(16) short xs[64][104];
    short (*ps)[72] = (short(*)[72])xs;
    __shared__ int   cnt_s[64];
    __shared__ float mean_s[64], rstd_s[64];

    const int tid  = threadIdx.x;
    const int wave = tid >> 6, lane = tid & 63;
    const int l16  = lane & 15, q8 = (lane >> 4) * 8, q4 = (lane >> 4) * 4;
    const int t0   = wave * 16;

    const short* qkvw_bf  = wsw + WO_QKVW;
    const short* projw_bf = wsw + WO_PROJW;

    const int wi = blockIdx.x;
    const int b  = wi >> 10, nw = wi & 1023;
    const int wh = nw >> 5, ww = nw & 31;
    const bool edge = (wh == 31) || (ww == 31);

    if (tid < 64) {
        int t = (tid < 49) ? tid : 48;
        int r = t / 7, c = t - r * 7;
        int sh = wh * 7 + r, sw = ww * 7 + c;
        int rh = (sh < 217) ? 0 : ((sh < 221) ? 1 : 2);
        int rw = (sw < 217) ? 0 : ((sw < 221) ? 1 : 2);
        cnt_s[tid] = rh * 3 + rw;
    }
    {
        int t = lane;
        int r = t / 7, cc = t - r * 7;
        int hh = wh * 7 + r + 3;  if (hh >= D_H) hh -= D_H;
        int w2 = ww * 7 + cc + 3; if (w2 >= D_W) w2 -= D_W;
        int off0 = (b * 96) * D_HW + hh * D_W + w2;
#pragma unroll
        for (int n = 0; n < 6; n++) {
            int c0 = wave * 24 + n * 4;
            s16x4 v4 = {0, 0, 0, 0};
            if (t < 49) {
                v4[0] = f2s(x[off0 + (c0 + 0) * D_HW]);
                v4[1] = f2s(x[off0 + (c0 + 1) * D_HW]);
                v4[2] = f2s(x[off0 + (c0 + 2) * D_HW]);
                v4[3] = f2s(x[off0 + (c0 + 3) * D_HW]);
            }
            *(s16x4*)&xs[t][c0] = v4;
        }
    }
    __syncthreads();
    {
        int t = tid >> 2, p = tid & 3;
        float s = 0.f, s2 = 0.f;
#pragma unroll
        for (int i = 0; i < 6; i++) {
            s16x4 v4 = *(const s16x4*)&xs[t][p * 24 + i * 4];
#pragma unroll
            for (int j = 0; j < 4; j++) { float v = s2f(v4[j]); s += v; s2 += v * v; }
        }
        s += __shfl_xor(s, 1); s2 += __shfl_xor(s2, 1);
        s += __shfl_xor(s, 2); s2 += __shfl_xor(s2, 2);
        if (p == 0) {
            float m = s * (1.f / 96.f);
            float var = s2 * (1.f / 96.f) - m * m;
            mean_s[t] = m; rstd_s[t] = rsqrtf(var + 1e-5f);
        }
    }
    __syncthreads();

    const float m0 = mean_s[t0 + l16], rs0 = rstd_s[t0 + l16];
    short8 a0 = normfrag(&xs[t0 + l16][q8],      n1g, n1b, q8,      m0, rs0);
    short8 a1 = normfrag(&xs[t0 + l16][32 + q8], n1g, n1b, 32 + q8, m0, rs0);
    short8 a2 = normfrag(&xs[t0 + l16][64 + q8], n1g, n1b, 64 + q8, m0, rs0);

#pragma unroll
    for (int jc = 0; jc < 3; jc++) {
#pragma unroll
        for (int nt = 0; nt < 6; nt++) {
            int jj = nt * 16 + l16;
            const short* wr = qkvw_bf + (jc * 96 + jj) * 96;
            f32x4 acc = {0.f, 0.f, 0.f, 0.f};
            acc = MFMA(a0, *(const short8*)&wr[q8],      acc);
            acc = MFMA(a1, *(const short8*)&wr[32 + q8], acc);
            acc = MFMA(a2, *(const short8*)&wr[64 + q8], acc);
            float bias = qkvb[jc * 96 + jj];
            if (jc == 0) {
#pragma unroll
                for (int r = 0; r < 4; r++) qk[t0 + q4 + r][jj] = f2s((acc[r] + bias) * SCALE);
            } else if (jc == 1) {
#pragma unroll
                for (int r = 0; r < 4; r++) qk[t0 + q4 + r][96 + jj] = f2s(acc[r] + bias);
            } else {
                s16x4 v4;
#pragma unroll
                for (int r = 0; r < 4; r++) v4[r] = f2s(acc[r] + bias);
                *(s16x4*)&vt[jj][t0 + q4] = v4;
            }
        }
    }

    float biasv[4][4][3];
#pragma unroll
    for (int nt = 0; nt < 4; nt++) {
        int m  = nt * 16 + l16;
        int mm = (m < 49) ? m : 48;
        int r2 = mm / 7, c2 = mm - r2 * 7;
        int cm = cnt_s[m];
#pragma unroll
        for (int r = 0; r < 4; r++) {
            int n  = t0 + q4 + r;
            int nn = (n < 49) ? n : 48;
            int r1 = nn / 7, c1 = nn - r1 * 7;
            int ri = ((r1 - r2 + 6) * 13 + (c1 - c2 + 6)) * 3;
            float mk = (edge && (cnt_s[n] != cm)) ? -100.f : 0.f;
            biasv[nt][r][0] = relt[ri + 0] + mk;
            biasv[nt][r][1] = relt[ri + 1] + mk;
            biasv[nt][r][2] = relt[ri + 2] + mk;
        }
    }
    const bool inval3 = (l16 != 0);

#pragma unroll
    for (int h = 0; h < 3; h++) {
        __syncthreads();
        short8 aq = *(const short8*)&qk[t0 + l16][h * 32 + q8];
        f32x4 sv[4];
#pragma unroll
        for (int nt = 0; nt < 4; nt++) {
            f32x4 z = {0.f, 0.f, 0.f, 0.f};
            sv[nt] = MFMA(aq, *(const short8*)&qk[nt * 16 + l16][96 + h * 32 + q8], z);
        }
        float mx[4] = {-1e30f, -1e30f, -1e30f, -1e30f};
#pragma unroll
        for (int nt = 0; nt < 4; nt++) {
#pragma unroll
            for (int r = 0; r < 4; r++) {
                float v = sv[nt][r] + biasv[nt][r][h];
                if (nt == 3 && inval3) v = -1e30f;
                sv[nt][r] = v;
                mx[r] = fmaxf(mx[r], v);
            }
        }
#pragma unroll
        for (int d = 1; d < 16; d <<= 1) {
#pragma unroll
            for (int r = 0; r < 4; r++) mx[r] = fmaxf(mx[r], __shfl_xor(mx[r], d));
        }
        float sm[4] = {0.f, 0.f, 0.f, 0.f};
#pragma unroll
        for (int nt = 0; nt < 4; nt++) {
#pragma unroll
            for (int r = 0; r < 4; r++) {
                float e = (nt == 3 && inval3) ? 0.f : __expf(sv[nt][r] - mx[r]);
                sv[nt][r] = e;
                sm[r] += e;
            }
        }
#pragma unroll
        for (int d = 1; d < 16; d <<= 1) {
#pragma unroll
            for (int r = 0; r < 4; r++) sm[r] += __shfl_xor(sm[r], d);
        }
        float inv[4];
#pragma unroll
        for (int r = 0; r < 4; r++) inv[r] = 1.f / sm[r];
#pragma unroll
        for (int nt = 0; nt < 4; nt++) {
#pragma unroll
            for (int r = 0; r < 4; r++)
                ps[t0 + q4 + r][nt * 16 + l16] = f2s(sv[nt][r] * inv[r]);
        }
        __syncthreads();
        short8 p0 = *(const short8*)&ps[t0 + l16][q8];
        short8 p1 = *(const short8*)&ps[t0 + l16][32 + q8];
#pragma unroll
        for (int nt = 0; nt < 2; nt++) {
            f32x4 acc = {0.f, 0.f, 0.f, 0.f};
            acc = MFMA(p0, *(const short8*)&vt[h * 32 + nt * 16 + l16][q8],      acc);
            acc = MFMA(p1, *(const short8*)&vt[h * 32 + nt * 16 + l16][32 + q8], acc);
            int d = nt * 16 + l16;
#pragma unroll
            for (int r = 0; r < 4; r++) {
                int t = t0 + q4 + r;
                if (t < 49) qk[t][h * 32 + d] = f2s(acc[r]);
            }
        }
    }

    __syncthreads();
    short8 o0 = *(const short8*)&qk[t0 + l16][q8];
    short8 o1 = *(const short8*)&qk[t0 + l16][32 + q8];
    short8 o2 = *(const short8*)&qk[t0 + l16][64 + q8];
    int  po[4];
    bool tv[4];
#pragma unroll
    for (int r = 0; r < 4; r++) {
        int t = t0 + q4 + r;
        tv[r] = (t < 49);
        int tt = tv[r] ? t : 0;
        int rr = tt / 7, cc = tt - rr * 7;
        int hh = wh * 7 + rr + 3;  if (hh >= D_H) hh -= D_H;
        int w2 = ww * 7 + cc + 3;  if (w2 >= D_W) w2 -= D_W;
        po[r] = (b * 96) * D_HW + hh * D_W + w2;
    }
#pragma unroll
    for (int nt = 0; nt < 6; nt++) {
        int i = nt * 16 + l16;
        const short* wr = projw_bf + i * 96;
        f32x4 acc = {0.f, 0.f, 0.f, 0.f};
        acc = MFMA(o0, *(const short8*)&wr[q8],      acc);
        acc = MFMA(o1, *(const short8*)&wr[32 + q8], acc);
        acc = MFMA(o2, *(const short8*)&wr[64 + q8], acc);
        float pb = projb[i];
#pragma unroll
        for (int r = 0; r < 4; r++) {
            if (tv[r]) {
                int off = po[r] + i * D_HW;
                y[off] = x[off] + acc[r] + pb;
            }
        }
    }
}

__global__ __launch_bounds__(256, 3) void k_mlp_f(
    float* __restrict__ y, const float* __restrict__ n2g, const float* __restrict__ n2b,
    const float* __restrict__ b1, const float* __restrict__ b2, const short* __restrict__ wsw)
{
    __shared__ short xs[128][104];
    __shared__ short hb[128][104];
    __shared__ float mean_s[128], rstd_s[128];

    const int tid  = threadIdx.x;
    const int wave = tid >> 6, lane = tid & 63;
    const int l16  = lane & 15, q8 = (lane >> 4) * 8, q4 = (lane >> 4) * 4;
    const int t0   = wave * 32;

    const short* w1_bf = wsw + WO_W1;
    const short* w2_bf = wsw + WO_W2;

    const int T0 = blockIdx.x * 128;
    const int b  = T0 / D_HW;
    const int p0 = T0 - b * D_HW;
    const int base = (b * 96) * D_HW + p0;

    for (int idx = tid; idx < 96 * 32; idx += 256) {
        int c = idx >> 5, q = idx & 31;
        f32x4 v4 = *(const f32x4*)&y[base + c * D_HW + q * 4];
        xs[q * 4 + 0][c] = f2s(v4[0]);
        xs[q * 4 + 1][c] = f2s(v4[1]);
        xs[q * 4 + 2][c] = f2s(v4[2]);
        xs[q * 4 + 3][c] = f2s(v4[3]);
    }
    __syncthreads();
    {
        int t = tid >> 1, p = tid & 1;
        float s = 0.f, s2 = 0.f;
#pragma unroll
        for (int i = 0; i < 12; i++) {
            s16x4 v4 = *(const s16x4*)&xs[t][p * 48 + i * 4];
#pragma unroll
            for (int j = 0; j < 4; j++) { float v = s2f(v4[j]); s += v; s2 += v * v; }
        }
        s += __shfl_xor(s, 1); s2 += __shfl_xor(s2, 1);
        float m = s * (1.f / 96.f);
        float var = s2 * (1.f / 96.f) - m * m;
        mean_s[t] = m; rstd_s[t] = rsqrtf(var + 1e-5f);
    }
    __syncthreads();

    short8 xa[2][3];
#pragma unroll
    for (int s = 0; s < 2; s++) {
        float m = mean_s[t0 + s * 16 + l16], rs = rstd_s[t0 + s * 16 + l16];
#pragma unroll
        for (int kk = 0; kk < 3; kk++)
            xa[s][kk] = normfrag(&xs[t0 + s * 16 + l16][kk * 32 + q8], n2g, n2b,
                                 kk * 32 + q8, m, rs);
    }

    f32x4 c2[2][6];
#pragma unroll
    for (int s = 0; s < 2; s++)
#pragma unroll
        for (int nt = 0; nt < 6; nt++) c2[s][nt] = (f32x4){0.f, 0.f, 0.f, 0.f};

    for (int jc = 0; jc < 4; jc++) {
#pragma unroll
        for (int s = 0; s < 2; s++) {
#pragma unroll
            for (int nt = 0; nt < 6; nt++) {
                int jj = nt * 16 + l16;
                const short* wr = w1_bf + (jc * 96 + jj) * 96;
                f32x4 acc = {0.f, 0.f, 0.f, 0.f};
                acc = MFMA(xa[s][0], *(const short8*)&wr[q8],      acc);
                acc = MFMA(xa[s][1], *(const short8*)&wr[32 + q8], acc);
                acc = MFMA(xa[s][2], *(const short8*)&wr[64 + q8], acc);
                float bb = b1[jc * 96 + jj];
#pragma unroll
                for (int r = 0; r < 4; r++) {
                    float v = acc[r] + bb;
                    float g = 0.5f * v * (1.f + erf_fast(v * 0.7071067811865475f));
                    hb[t0 + s * 16 + q4 + r][jj] = f2s(g);
                }
            }
        }
        __syncthreads();
#pragma unroll
        for (int s = 0; s < 2; s++) {
            short8 h0 = *(const short8*)&hb[t0 + s * 16 + l16][q8];
            short8 h1 = *(const short8*)&hb[t0 + s * 16 + l16][32 + q8];
            short8 h2 = *(const short8*)&hb[t0 + s * 16 + l16][64 + q8];
#pragma unroll
            for (int nt = 0; nt < 6; nt++) {
                const short* wr = w2_bf + (nt * 16 + l16) * 384 + jc * 96;
                c2[s][nt] = MFMA(h0, *(const short8*)&wr[q8],      c2[s][nt]);
                c2[s][nt] = MFMA(h1, *(const short8*)&wr[32 + q8], c2[s][nt]);
                c2[s][nt] = MFMA(h2, *(const short8*)&wr[64 + q8], c2[s][nt]);
            }
        }
        __syncthreads();
    }

#pragma unroll
    for (int s = 0; s < 2; s++)
#pragma unroll
        for (int nt = 0; nt < 6; nt++) {
            int i = nt * 16 + l16;
            float bo = b2[i];
#pragma unroll
            for (int r = 0; r < 4; r++)
                xs[t0 + s * 16 + q4 + r][i] = f2s(bo + c2[s][nt][r]);
        }
    __syncthreads();
    for (int idx = tid; idx < 96 * 32; idx += 256) {
        int c = idx >> 5, q = idx & 31;
        int off = base + c * D_HW + q * 4;
        f32x4 v4 = *(const f32x4*)&y[off];
        v4[0] += s2f(xs[q * 4 + 0][c]);
        v4[1] += s2f(xs[q * 4 + 1][c]);
        v4[2] += s2f(xs[q * 4 + 2][c]);
        v4[3] += s2f(xs[q * 4 + 3][c]);
        *(f32x4*)&y[off] = v4;
    }
}

extern "C" void kernel_launch(void* const* d_in, const int* in_sizes, int n_in,
                              void* d_out, int out_size, void* d_ws, size_t ws_size,
                              hipStream_t stream) {
    const float* x    = (const float*)d_in[0];
    const float* n1g  = (const float*)d_in[1];
    const float* n1b  = (const float*)d_in[2];
    const float* qkvw = (const float*)d_in[3];
    const float* qkvb = (const float*)d_in[4];
    const float* relt = (const float*)d_in[5];
    const float* projw= (const float*)d_in[6];
    const float* projb= (const float*)d_in[7];
    const float* n2g  = (const float*)d_in[8];
    const float* n2b  = (const float*)d_in[9];
    const float* w1   = (const float*)d_in[10];
    const float* b1   = (const float*)d_in[11];
    const float* w2   = (const float*)d_in[12];
    const float* b2   = (const float*)d_in[13];
    float* y  = (float*)d_out;
    short* ws = (short*)d_ws;

    if (ws_size >= WS_NEED) {
        short* xt  = ws + XT_SH;
        short* ytk = ws + YT_SH;
        short* wbf = ws + W_SH;
        k_t<<<1900, 256, 0, stream>>>(x, n1g, n1b, xt, qkvw, projw, w1, w2, wbf);
        k_attn_t<<<8192, 256, 0, stream>>>(xt, qkvb, relt, projb, wbf, ytk);
        k_mlp_t<<<6272, 256, 0, stream>>>(x, ytk, y, n2g, n2b, b1, b2, wbf);
    } else {
        k_prep<<<108, 256, 0, stream>>>(qkvw, projw, w1, w2, ws);
        k_attn_f<<<8192, 256, 0, stream>>>(x, n1g, n1b, qkvb, relt, projb, ws, y);
        k_mlp_f<<<3136, 256, 0, stream>>>(y, n2g, n2b, b1, b2, ws);
    }
}